// Round 11
// baseline (7881.503 us; speedup 1.0000x reference)
//
#include <hip/hip_runtime.h>
#include <stdint.h>
#include <stddef.h>

// Problem dims
#define Mdim 2048
#define Tdim 64
#define INdim 16
#define Hdim 256
#define NCdim 64

#define NUG 64
#define HSLAB (256 * 2048)            // 524288
#define RSLOTS 16
#define S0P 276
#define S1P 516
#define SLICE (16*S0P + 16*S1P + 32)  // kept only to preserve ws offsets

// ws layout (float offsets)
// Weight tables (fit inside old NUG*SLICE region):
#define OFF_WZ    0                             // [64 ug][16 k][16 g]
#define OFF_TL0   (OFF_WZ + 64 * 256)           // [64 ug][32 kk][8 k][16 g]
#define OFF_TIH1  (OFF_TL0 + 64 * 4096)
#define OFF_TH1   (OFF_TIH1 + 64 * 4096)
#define OFF_B0    (OFF_TH1 + 64 * 4096)         // [64 ug][16]
#define OFF_B1    (OFF_B0 + 1024)
#define OFF_WFCP  (NUG * SLICE)                 // [256 k][64 c] float4 {g,s,m,0}
#define OFF_H0    (OFF_WFCP + 256 * 64 * 4)     // [2][256 u][2048 m]
#define OFF_C0    (OFF_H0 + 2 * HSLAB)
#define OFF_C1    (OFF_C0 + HSLAB)
#define OFF_RING  (OFF_C1 + HSLAB)              // [16][256 u][2048 m]
#define OFF_RING2 (OFF_RING + RSLOTS * HSLAB)   // [16][2048 m][256 u]
#define WS_TOT    (OFF_RING2 + RSLOTS * HSLAB)  // ~79 MB

#define ROTL32(v, s) (((v) << (s)) | ((v) >> (32 - (s))))

// JAX threefry2x32
__host__ __device__ inline void tf2x32(uint32_t k0, uint32_t k1, uint32_t x0, uint32_t x1,
                                       uint32_t* o0, uint32_t* o1) {
  uint32_t ks2 = k0 ^ k1 ^ 0x1BD11BDAu;
  x0 += k0; x1 += k1;
  x0 += x1; x1 = ROTL32(x1, 13); x1 ^= x0;
  x0 += x1; x1 = ROTL32(x1, 15); x1 ^= x0;
  x0 += x1; x1 = ROTL32(x1, 26); x1 ^= x0;
  x0 += x1; x1 = ROTL32(x1, 6);  x1 ^= x0;
  x0 += k1; x1 += ks2 + 1u;
  x0 += x1; x1 = ROTL32(x1, 17); x1 ^= x0;
  x0 += x1; x1 = ROTL32(x1, 29); x1 ^= x0;
  x0 += x1; x1 = ROTL32(x1, 16); x1 ^= x0;
  x0 += x1; x1 = ROTL32(x1, 24); x1 ^= x0;
  x0 += ks2; x1 += k0 + 2u;
  x0 += x1; x1 = ROTL32(x1, 13); x1 ^= x0;
  x0 += x1; x1 = ROTL32(x1, 15); x1 ^= x0;
  x0 += x1; x1 = ROTL32(x1, 26); x1 ^= x0;
  x0 += x1; x1 = ROTL32(x1, 6);  x1 ^= x0;
  x0 += k0; x1 += k1 + 3u;
  x0 += x1; x1 = ROTL32(x1, 17); x1 ^= x0;
  x0 += x1; x1 = ROTL32(x1, 29); x1 ^= x0;
  x0 += x1; x1 = ROTL32(x1, 16); x1 ^= x0;
  x0 += x1; x1 = ROTL32(x1, 24); x1 ^= x0;
  x0 += k1; x1 += ks2 + 4u;
  x0 += x1; x1 = ROTL32(x1, 13); x1 ^= x0;
  x0 += x1; x1 = ROTL32(x1, 15); x1 ^= x0;
  x0 += x1; x1 = ROTL32(x1, 26); x1 ^= x0;
  x0 += x1; x1 = ROTL32(x1, 6);  x1 ^= x0;
  x0 += ks2; x1 += k0 + 5u;
  *o0 = x0; *o1 = x1;
}

__device__ inline uint32_t random_bits32(uint32_t ka, uint32_t kb, uint32_t p) {
  uint32_t a, b;
  tf2x32(ka, kb, 0u, p, &a, &b);
  return a ^ b;
}

__device__ inline float bits_to_u01(uint32_t bits) {
  return __uint_as_float((bits >> 9) | 0x3f800000u) - 1.0f;
}

__device__ inline float sigm_fast(float x) { return 1.0f / (1.0f + __expf(-x)); }

__device__ inline float erfinv_f32(float x) {
  float w = -log1pf(-x * x);
  float p;
  if (w < 5.0f) {
    w -= 2.5f;
    p = 2.81022636e-08f;
    p = fmaf(p, w, 3.43273939e-07f);
    p = fmaf(p, w, -3.5233877e-06f);
    p = fmaf(p, w, -4.39150654e-06f);
    p = fmaf(p, w, 0.00021858087f);
    p = fmaf(p, w, -0.00125372503f);
    p = fmaf(p, w, -0.00417768164f);
    p = fmaf(p, w, 0.246640727f);
    p = fmaf(p, w, 1.50140941f);
  } else {
    w = sqrtf(w) - 3.0f;
    p = -0.000200214257f;
    p = fmaf(p, w, 0.000100950558f);
    p = fmaf(p, w, 0.00134934322f);
    p = fmaf(p, w, -0.00367342844f);
    p = fmaf(p, w, 0.00573950773f);
    p = fmaf(p, w, -0.0076224613f);
    p = fmaf(p, w, 0.00943887047f);
    p = fmaf(p, w, 1.00167406f);
    p = fmaf(p, w, 2.83297682f);
  }
  return p * x;
}

__device__ inline void mdn_head(float yg, float ysg, float ym, int lane, uint32_t rid,
                                uint32_t k1a, uint32_t k1b, uint32_t k2a, uint32_t k2b,
                                float* __restrict__ out) {
  uint32_t pp = rid * (uint32_t)NCdim + (uint32_t)lane;
  uint32_t bits = random_bits32(k1a, k1b, pp);
  float u01 = bits_to_u01(bits);
  const float tinyf = 1.17549435e-38f;
  float uu = fmaxf(tinyf, u01 + tinyf);
  float gum = -logf(-logf(uu));
  float val = gum + yg;
  int idx = lane;
#pragma unroll
  for (int s = 1; s < 64; s <<= 1) {
    float ov = __shfl_xor(val, s);
    int oi = __shfl_xor(idx, s);
    if (ov > val || (ov == val && oi < idx)) { val = ov; idx = oi; }
  }
  float mu_sel = __shfl(ym, idx);
  float s_sel = __shfl(ysg, idx);

  uint32_t ebits = random_bits32(k2a, k2b, rid);
  float ue = bits_to_u01(ebits);
  const float lo = __uint_as_float(0xBF7FFFFFu);
  float un2 = fmaxf(lo, ue * 2.0f + lo);
  float eps = 1.41421356f * erfinv_f32(un2);

  float x_pred = mu_sel + expf(s_sel) * eps;

  float mx = yg;
#pragma unroll
  for (int s = 1; s < 64; s <<= 1) mx = fmaxf(mx, __shfl_xor(mx, s));
  float se = expf(yg - mx);
#pragma unroll
  for (int s = 1; s < 64; s <<= 1) se += __shfl_xor(se, s);
  float d = x_pred - ym;
  float lk = -0.5f * d * d - 66.0f * ysg - 58.812066f;
  float ts = expf(yg - mx + lk);
#pragma unroll
  for (int s = 1; s < 64; s <<= 1) ts += __shfl_xor(ts, s);
  float prob = ts / se;

  if (lane == 0) {
    out[rid] = x_pred;
    out[(size_t)Mdim * Tdim + rid] = prob;
  }
}

// Pack class-major weight tables + FC table.
// local gate g = u_local*4 + ty (ty: 0=i,1=f,2=g,3=o); gd = ty*256 + ug*4 + u_local.
__global__ void vfpg_prep(const float* __restrict__ Wih0, const float* __restrict__ Whh0,
                          const float* __restrict__ Wih1, const float* __restrict__ Whh1,
                          const float* __restrict__ fcW, const float* __restrict__ bih0,
                          const float* __restrict__ bhh0, const float* __restrict__ bih1,
                          const float* __restrict__ bhh1, float* __restrict__ ws) {
  int i0 = blockIdx.x * blockDim.x + threadIdx.x;
  int n = blockDim.x * gridDim.x;
  for (int i = i0; i < 64 * 256; i += n) {     // WZ [ug][k16][g16]
    int ug = i >> 8, k = (i >> 4) & 15, g = i & 15;
    int gd = (g & 3) * 256 + ug * 4 + (g >> 2);
    ws[OFF_WZ + i] = Wih0[gd * INdim + k];
  }
  for (int i = i0; i < 64 * 4096; i += n) {    // [ug][kk32][k8][g16]
    int ug = i >> 12, kk = (i >> 7) & 31, k = (i >> 4) & 7, g = i & 15;
    int gd = (g & 3) * 256 + ug * 4 + (g >> 2);
    int krow = kk * 8 + k;
    ws[OFF_TL0 + i]  = Whh0[gd * Hdim + krow];
    ws[OFF_TIH1 + i] = Wih1[gd * Hdim + krow];
    ws[OFF_TH1 + i]  = Whh1[gd * Hdim + krow];
  }
  for (int i = i0; i < 1024; i += n) {         // biases [ug][g16]
    int ug = i >> 4, g = i & 15;
    int gd = (g & 3) * 256 + ug * 4 + (g >> 2);
    ws[OFF_B0 + i] = bih0[gd] + bhh0[gd];
    ws[OFF_B1 + i] = bih1[gd] + bhh1[gd];
  }
  float4* wfcp = (float4*)(ws + OFF_WFCP);
  for (int o = i0; o < 256 * 64; o += n) {
    int k = o >> 6, c = o & 63;
    wfcp[o] = make_float4(fcW[c * Hdim + k], fcW[(64 + c) * Hdim + k],
                          fcW[(128 + c) * Hdim + k], 0.0f);
  }
}

__device__ inline void fma16(float* a, float h, float4 w0, float4 w1, float4 w2, float4 w3) {
  a[0] = fmaf(h, w0.x, a[0]);  a[1] = fmaf(h, w0.y, a[1]);
  a[2] = fmaf(h, w0.z, a[2]);  a[3] = fmaf(h, w0.w, a[3]);
  a[4] = fmaf(h, w1.x, a[4]);  a[5] = fmaf(h, w1.y, a[5]);
  a[6] = fmaf(h, w1.z, a[6]);  a[7] = fmaf(h, w1.w, a[7]);
  a[8] = fmaf(h, w2.x, a[8]);  a[9] = fmaf(h, w2.y, a[9]);
  a[10] = fmaf(h, w2.z, a[10]); a[11] = fmaf(h, w2.w, a[11]);
  a[12] = fmaf(h, w3.x, a[12]); a[13] = fmaf(h, w3.y, a[13]);
  a[14] = fmaf(h, w3.z, a[14]); a[15] = fmaf(h, w3.w, a[15]);
}

__device__ inline void cell1(float4 g4, float cold, float* cn, float* hn) {
  float si = sigm_fast(g4.x), sf = sigm_fast(g4.y);
  float tg = fmaf(2.0f, sigm_fast(2.0f * g4.z), -1.0f);
  float so = sigm_fast(g4.w);
  float cc = fmaf(sf, cold, si * tg);
  *cn = cc;
  *hn = so * fmaf(2.0f, sigm_fast(2.0f * cc), -1.0f);
}

// Launch t: layer0 step t (h0(t)) + layer1 step t-1 (h1(t-1)).
// MODE 0: t=0 (L0 only); 1: 1..63 (both); 2: t=64 (L1 only).
// 256 threads, 4 waves: gs=wid&1 (gate-class), rh=wid>>1 (row half).
// Lane: rows mr, mr+1; 16 gates (4 units x ifgo) lane-local.
template <int MODE>
__launch_bounds__(256, 2)
__global__ void vfpg_step(const float* __restrict__ z, const float* __restrict__ ws,
                          float* __restrict__ h0buf, float* __restrict__ c0w,
                          float* __restrict__ c1w, float* __restrict__ ring,
                          float* __restrict__ ring2, int t) {
  constexpr bool DO_L0 = (MODE <= 1);
  constexpr bool DO_L1 = (MODE >= 1);
  __shared__ __align__(16) float sbuf[4096];   // 16 KB: staging dbuf / hh1 exchange

  const int tid = threadIdx.x;
  const int rg = blockIdx.x & 7, ug = blockIdx.x >> 3;
  const int mb = rg * 256;
  const int lane = tid & 63, wid = tid >> 6;
  const int gs = wid & 1, rh = wid >> 1;
  const int rbase = rh * 128 + 2 * lane;
  const int mr = mb + rbase;
  const int kst = tid >> 6, m4 = (tid & 63) * 4;

  const float* TWH0 = ws + (gs ? OFF_TIH1 : OFF_TL0) + (size_t)ug * 4096;
  const float* TWH1 = ws + OFF_TH1 + (size_t)ug * 4096;
  const float* BV = ws + (gs ? OFF_B1 : OFF_B0) + (size_t)ug * 16;

  // af: gs0 -> L0 gates; gs1 -> b1 + ih1 (later + hh1)
  float af[2][16];
#pragma unroll
  for (int g = 0; g < 16; g++) { float b = BV[g]; af[0][g] = b; af[1][g] = b; }

  // ---- Z phase (gs0 only): af += Wz . z(t) ----
  if (DO_L0 && gs == 0) {
    const float* TWZ = ws + OFF_WZ + (size_t)ug * 256;
    float zr[2][16];
#pragma unroll
    for (int j = 0; j < 2; j++)
#pragma unroll
      for (int f4 = 0; f4 < 4; f4++)
        *(float4*)&zr[j][f4 * 4] =
            *(const float4*)&z[(size_t)(mr + j) * 1024 + t * 16 + f4 * 4];
#pragma unroll
    for (int k = 0; k < 16; k++) {
      const float4* wp = (const float4*)(TWZ + k * 16);
      float4 w0 = wp[0], w1 = wp[1], w2 = wp[2], w3 = wp[3];
      fma16(af[0], zr[0][k], w0, w1, w2, w3);
      fma16(af[1], zr[1][k], w0, w1, w2, w3);
    }
  }

  // ---- H0 phase: h0(t-1) panel, 32 chunks; gs0 -> L0, gs1 -> ih1 ----
  if (MODE >= 1) {
    const float* h0p = h0buf + (size_t)((t - 1) & 1) * HSLAB + mb;
    float4 s0 = *(const float4*)&h0p[(size_t)kst * 2048 + m4];
    float4 s1 = *(const float4*)&h0p[(size_t)(kst + 4) * 2048 + m4];
    const bool doH0 = DO_L0 || gs == 1;
#pragma unroll 1
    for (int kk = 0; kk < 32; kk++) {
      float* buf = sbuf + (kk & 1) * 2048;
      *(float4*)&buf[kst * 256 + m4] = s0;
      *(float4*)&buf[(kst + 4) * 256 + m4] = s1;
      if (kk < 31) {
        s0 = *(const float4*)&h0p[(size_t)(kk * 8 + 8 + kst) * 2048 + m4];
        s1 = *(const float4*)&h0p[(size_t)(kk * 8 + 12 + kst) * 2048 + m4];
      }
      // batch this chunk's weights (wave-uniform) before the barrier
      const float4* wt = (const float4*)(TWH0 + (size_t)kk * 128);
      __syncthreads();
      if (doH0) {
#pragma unroll
        for (int k = 0; k < 8; k++) {
          float2 hh = *(const float2*)&buf[k * 256 + rbase];
          float4 w0 = wt[k * 4], w1 = wt[k * 4 + 1], w2 = wt[k * 4 + 2], w3 = wt[k * 4 + 3];
          fma16(af[0], hh.x, w0, w1, w2, w3);
          fma16(af[1], hh.y, w0, w1, w2, w3);
        }
      }
    }
  }

  // ---- L0 cell update (gs0, lane-local ifgo x 4 units) ----
  if (DO_L0 && gs == 0) {
    float* h0c = h0buf + (size_t)(t & 1) * HSLAB;
#pragma unroll
    for (int u = 0; u < 4; u++) {
      size_t idx = (size_t)(ug * 4 + u) * 2048 + mr;
      float2 cold = make_float2(0.0f, 0.0f);
      if (MODE == 1) cold = *(const float2*)&c0w[idx];
      float2 cn, hn;
      cell1(make_float4(af[0][u * 4], af[0][u * 4 + 1], af[0][u * 4 + 2], af[0][u * 4 + 3]),
            cold.x, &cn.x, &hn.x);
      cell1(make_float4(af[1][u * 4], af[1][u * 4 + 1], af[1][u * 4 + 2], af[1][u * 4 + 3]),
            cold.y, &cn.y, &hn.y);
      *(float2*)&c0w[idx] = cn;
      *(float2*)&h0c[idx] = hn;
    }
  }

  // ---- H1 phase: h1(t-2) panel; hh1 k-split: gs0 chunks 0..15, gs1 16..31 ----
  float ah[2][16];
#pragma unroll
  for (int g = 0; g < 16; g++) { ah[0][g] = 0.0f; ah[1][g] = 0.0f; }
  if (DO_L1 && t >= 2) {
    const float* h1p = ring + (size_t)((t - 2) & 15) * HSLAB + mb;
    float4 s0 = *(const float4*)&h1p[(size_t)kst * 2048 + m4];
    float4 s1 = *(const float4*)&h1p[(size_t)(kst + 4) * 2048 + m4];
#pragma unroll 1
    for (int kk = 0; kk < 32; kk++) {
      float* buf = sbuf + (kk & 1) * 2048;
      *(float4*)&buf[kst * 256 + m4] = s0;
      *(float4*)&buf[(kst + 4) * 256 + m4] = s1;
      if (kk < 31) {
        s0 = *(const float4*)&h1p[(size_t)(kk * 8 + 8 + kst) * 2048 + m4];
        s1 = *(const float4*)&h1p[(size_t)(kk * 8 + 12 + kst) * 2048 + m4];
      }
      const float4* wt = (const float4*)(TWH1 + (size_t)kk * 128);
      __syncthreads();
      if ((kk >> 4) == gs) {
#pragma unroll
        for (int k = 0; k < 8; k++) {
          float2 hh = *(const float2*)&buf[k * 256 + rbase];
          float4 w0 = wt[k * 4], w1 = wt[k * 4 + 1], w2 = wt[k * 4 + 2], w3 = wt[k * 4 + 3];
          fma16(ah[0], hh.x, w0, w1, w2, w3);
          fma16(ah[1], hh.y, w0, w1, w2, w3);
        }
      }
    }
  }

  // ---- hh1 exchange + L1 cell update (gs1, lane-local) ----
  if (DO_L1) {
    __syncthreads();   // drain H1 reads before overwriting sbuf
    if (gs == 0) {
#pragma unroll
      for (int g = 0; g < 16; g++)
        *(float2*)&sbuf[g * 256 + rbase] = make_float2(ah[0][g], ah[1][g]);
    }
    __syncthreads();
    if (gs == 1) {
      int slot = (t - 1) & 15;
      float* r1 = ring + (size_t)slot * HSLAB;
      float* r2 = ring2 + (size_t)slot * HSLAB;
#pragma unroll
      for (int g = 0; g < 16; g++) {
        float2 hp = *(const float2*)&sbuf[g * 256 + rbase];
        af[0][g] += ah[0][g] + hp.x;
        af[1][g] += ah[1][g] + hp.y;
      }
#pragma unroll
      for (int u = 0; u < 4; u++) {
        size_t idx = (size_t)(ug * 4 + u) * 2048 + mr;
        float2 cold = make_float2(0.0f, 0.0f);
        if (t >= 2) cold = *(const float2*)&c1w[idx];
        float2 cn, hn;
        cell1(make_float4(af[0][u * 4], af[0][u * 4 + 1], af[0][u * 4 + 2], af[0][u * 4 + 3]),
              cold.x, &cn.x, &hn.x);
        cell1(make_float4(af[1][u * 4], af[1][u * 4 + 1], af[1][u * 4 + 2], af[1][u * 4 + 3]),
              cold.y, &cn.y, &hn.y);
        *(float2*)&c1w[idx] = cn;
        *(float2*)&r1[idx] = hn;
        r2[(size_t)mr * 256 + ug * 4 + u] = hn.x;
        r2[(size_t)(mr + 1) * 256 + ug * 4 + u] = hn.y;
      }
    }
  }
}

// Head: FC + MDN for 16 slots x 2048 rows; wave = 8 rows. (unchanged)
__launch_bounds__(512, 2)
__global__ void vfpg_head(const float* __restrict__ ws, const float* __restrict__ fcb,
                          float* __restrict__ out, int tbase,
                          uint32_t k1a, uint32_t k1b, uint32_t k2a, uint32_t k2b) {
  __shared__ __align__(16) float hsw[8][8][Hdim];   // 64 KB
  const int tid = threadIdx.x;
  const int lane = tid & 63, wid = tid >> 6;
  const int rb8 = blockIdx.x * 8 + wid;
  const int slot = rb8 >> 8;
  const int mbase = (rb8 & 255) * 8;

  const float* r2 = ws + OFF_RING2 + (size_t)slot * HSLAB + (size_t)mbase * 256;
  const float4* WFCP = (const float4*)(ws + OFF_WFCP);

#pragma unroll
  for (int rr = 0; rr < 8; rr++)
    *(float4*)&hsw[wid][rr][lane * 4] = *(const float4*)&r2[rr * 256 + lane * 4];
  __builtin_amdgcn_s_waitcnt(0);

  float yg[8], ys[8], ym[8];
#pragma unroll
  for (int rr = 0; rr < 8; rr++) {
    yg[rr] = fcb[lane]; ys[rr] = fcb[64 + lane]; ym[rr] = fcb[128 + lane];
  }
#pragma unroll 2
  for (int k4 = 0; k4 < 64; k4++) {
#pragma unroll
    for (int j = 0; j < 4; j++) {
      float4 w = WFCP[(k4 * 4 + j) * 64 + lane];
#pragma unroll
      for (int rr = 0; rr < 8; rr++) {
        float hv = hsw[wid][rr][k4 * 4 + j];
        yg[rr] = fmaf(hv, w.x, yg[rr]);
        ys[rr] = fmaf(hv, w.y, ys[rr]);
        ym[rr] = fmaf(hv, w.z, ym[rr]);
      }
    }
  }
  int tt = tbase + slot;
#pragma unroll 1
  for (int rr = 0; rr < 8; rr++) {
    uint32_t rid = (uint32_t)(mbase + rr) * Tdim + (uint32_t)tt;
    mdn_head(yg[rr], ys[rr], ym[rr], lane, rid, k1a, k1b, k2a, k2b, out);
  }
}

extern "C" void kernel_launch(void* const* d_in, const int* in_sizes, int n_in,
                              void* d_out, int out_size, void* d_ws, size_t ws_size,
                              hipStream_t stream) {
  const float* z    = (const float*)d_in[0];
  const float* Wih0 = (const float*)d_in[1];
  const float* Whh0 = (const float*)d_in[2];
  const float* bih0 = (const float*)d_in[3];
  const float* bhh0 = (const float*)d_in[4];
  const float* Wih1 = (const float*)d_in[5];
  const float* Whh1 = (const float*)d_in[6];
  const float* bih1 = (const float*)d_in[7];
  const float* bhh1 = (const float*)d_in[8];
  const float* fcW  = (const float*)d_in[9];
  const float* fcb  = (const float*)d_in[10];
  float* ws = (float*)d_ws;
  float* out = (float*)d_out;

  if (ws_size < (size_t)WS_TOT * sizeof(float)) return;

  vfpg_prep<<<dim3(512), dim3(256), 0, stream>>>(
      Wih0, Whh0, Wih1, Whh1, fcW, bih0, bhh0, bih1, bhh1, ws);

  uint32_t k1a, k1b, k2a, k2b;
  tf2x32(0u, 42u, 0u, 0u, &k1a, &k1b);
  tf2x32(0u, 42u, 0u, 1u, &k2a, &k2b);

  float* h0buf = ws + OFF_H0;
  float* c0w = ws + OFF_C0;
  float* c1w = ws + OFF_C1;
  float* ring = ws + OFF_RING;
  float* ring2 = ws + OFF_RING2;

  vfpg_step<0><<<dim3(512), dim3(256), 0, stream>>>(z, ws, h0buf, c0w, c1w, ring, ring2, 0);
  for (int t = 1; t <= 63; t++) {
    vfpg_step<1><<<dim3(512), dim3(256), 0, stream>>>(z, ws, h0buf, c0w, c1w, ring, ring2, t);
    if (t == 16 || t == 32 || t == 48) {
      vfpg_head<<<dim3(512), dim3(512), 0, stream>>>(ws, fcb, out, t - 16,
                                                     k1a, k1b, k2a, k2b);
    }
  }
  vfpg_step<2><<<dim3(512), dim3(256), 0, stream>>>(z, ws, h0buf, c0w, c1w, ring, ring2, 64);
  vfpg_head<<<dim3(512), dim3(512), 0, stream>>>(ws, fcb, out, 48, k1a, k1b, k2a, k2b);
}

// Round 12
// 3471.782 us; speedup vs baseline: 2.2702x; 2.2702x over previous
//
#include <hip/hip_runtime.h>
#include <stdint.h>
#include <stddef.h>

// Problem dims
#define Mdim 2048
#define Tdim 64
#define INdim 16
#define Hdim 256
#define NCdim 64
#define NUG 64
#define HSLAB (256 * 2048)
#define RSLOTS 16

typedef __attribute__((ext_vector_type(8))) short s16x8;
typedef __attribute__((ext_vector_type(4))) float f32x4;

// Panel (per tbuf/slot, per rg): [sp3][mt16][kt8][512] bf16  -> 196608 ushorts
#define PANEL_US (3 * 16 * 8 * 512)
// BFRAG per ug: [cls3][kt8][sp3][512] bf16 -> 36864 ushorts
#define BFRAG_US (3 * 8 * 3 * 512)

// ws float offsets
#define OFF_BFRAG 0                                    // 64 * 36864 us = 1179648 fl
#define OFF_WZ    1179648                              // [64][16 k][16 g] fp32
#define OFF_BB    (OFF_WZ + 64 * 256)                  // [64][32]
#define OFF_WFCP  (OFF_BB + 64 * 32)                   // [256][64] float4
#define OFF_H0P   (OFF_WFCP + 256 * 64 * 4)            // [2 tbuf][8 rg] panels: 1572864 fl
#define OFF_C0    (OFF_H0P + 1572864)
#define OFF_C1    (OFF_C0 + HSLAB)
#define OFF_RINGF (OFF_C1 + HSLAB)                     // [16 slot][8 rg] panels: 12582912 fl
#define OFF_RING2 (OFF_RINGF + 12582912)               // fp32 [16][2048 m][256 u]
#define WS_TOT    (OFF_RING2 + RSLOTS * HSLAB)         // 24856576 fl = 99.4 MB (<137.7 proven)

#define ROTL32(v, s) (((v) << (s)) | ((v) >> (32 - (s))))

__host__ __device__ inline void tf2x32(uint32_t k0, uint32_t k1, uint32_t x0, uint32_t x1,
                                       uint32_t* o0, uint32_t* o1) {
  uint32_t ks2 = k0 ^ k1 ^ 0x1BD11BDAu;
  x0 += k0; x1 += k1;
  x0 += x1; x1 = ROTL32(x1, 13); x1 ^= x0;
  x0 += x1; x1 = ROTL32(x1, 15); x1 ^= x0;
  x0 += x1; x1 = ROTL32(x1, 26); x1 ^= x0;
  x0 += x1; x1 = ROTL32(x1, 6);  x1 ^= x0;
  x0 += k1; x1 += ks2 + 1u;
  x0 += x1; x1 = ROTL32(x1, 17); x1 ^= x0;
  x0 += x1; x1 = ROTL32(x1, 29); x1 ^= x0;
  x0 += x1; x1 = ROTL32(x1, 16); x1 ^= x0;
  x0 += x1; x1 = ROTL32(x1, 24); x1 ^= x0;
  x0 += ks2; x1 += k0 + 2u;
  x0 += x1; x1 = ROTL32(x1, 13); x1 ^= x0;
  x0 += x1; x1 = ROTL32(x1, 15); x1 ^= x0;
  x0 += x1; x1 = ROTL32(x1, 26); x1 ^= x0;
  x0 += x1; x1 = ROTL32(x1, 6);  x1 ^= x0;
  x0 += k0; x1 += k1 + 3u;
  x0 += x1; x1 = ROTL32(x1, 17); x1 ^= x0;
  x0 += x1; x1 = ROTL32(x1, 29); x1 ^= x0;
  x0 += x1; x1 = ROTL32(x1, 16); x1 ^= x0;
  x0 += x1; x1 = ROTL32(x1, 24); x1 ^= x0;
  x0 += k1; x1 += ks2 + 4u;
  x0 += x1; x1 = ROTL32(x1, 13); x1 ^= x0;
  x0 += x1; x1 = ROTL32(x1, 15); x1 ^= x0;
  x0 += x1; x1 = ROTL32(x1, 26); x1 ^= x0;
  x0 += x1; x1 = ROTL32(x1, 6);  x1 ^= x0;
  x0 += ks2; x1 += k0 + 5u;
  *o0 = x0; *o1 = x1;
}

__device__ inline uint32_t random_bits32(uint32_t ka, uint32_t kb, uint32_t p) {
  uint32_t a, b;
  tf2x32(ka, kb, 0u, p, &a, &b);
  return a ^ b;
}

__device__ inline float bits_to_u01(uint32_t bits) {
  return __uint_as_float((bits >> 9) | 0x3f800000u) - 1.0f;
}

__device__ inline float sigm_fast(float x) { return 1.0f / (1.0f + __expf(-x)); }

__device__ inline float erfinv_f32(float x) {
  float w = -log1pf(-x * x);
  float p;
  if (w < 5.0f) {
    w -= 2.5f;
    p = 2.81022636e-08f;
    p = fmaf(p, w, 3.43273939e-07f);
    p = fmaf(p, w, -3.5233877e-06f);
    p = fmaf(p, w, -4.39150654e-06f);
    p = fmaf(p, w, 0.00021858087f);
    p = fmaf(p, w, -0.00125372503f);
    p = fmaf(p, w, -0.00417768164f);
    p = fmaf(p, w, 0.246640727f);
    p = fmaf(p, w, 1.50140941f);
  } else {
    w = sqrtf(w) - 3.0f;
    p = -0.000200214257f;
    p = fmaf(p, w, 0.000100950558f);
    p = fmaf(p, w, 0.00134934322f);
    p = fmaf(p, w, -0.00367342844f);
    p = fmaf(p, w, 0.00573950773f);
    p = fmaf(p, w, -0.0076224613f);
    p = fmaf(p, w, 0.00943887047f);
    p = fmaf(p, w, 1.00167406f);
    p = fmaf(p, w, 2.83297682f);
  }
  return p * x;
}

__device__ inline void mdn_head(float yg, float ysg, float ym, int lane, uint32_t rid,
                                uint32_t k1a, uint32_t k1b, uint32_t k2a, uint32_t k2b,
                                float* __restrict__ out) {
  uint32_t pp = rid * (uint32_t)NCdim + (uint32_t)lane;
  uint32_t bits = random_bits32(k1a, k1b, pp);
  float u01 = bits_to_u01(bits);
  const float tinyf = 1.17549435e-38f;
  float uu = fmaxf(tinyf, u01 + tinyf);
  float gum = -logf(-logf(uu));
  float val = gum + yg;
  int idx = lane;
#pragma unroll
  for (int s = 1; s < 64; s <<= 1) {
    float ov = __shfl_xor(val, s);
    int oi = __shfl_xor(idx, s);
    if (ov > val || (ov == val && oi < idx)) { val = ov; idx = oi; }
  }
  float mu_sel = __shfl(ym, idx);
  float s_sel = __shfl(ysg, idx);

  uint32_t ebits = random_bits32(k2a, k2b, rid);
  float ue = bits_to_u01(ebits);
  const float lo = __uint_as_float(0xBF7FFFFFu);
  float un2 = fmaxf(lo, ue * 2.0f + lo);
  float eps = 1.41421356f * erfinv_f32(un2);

  float x_pred = mu_sel + expf(s_sel) * eps;

  float mx = yg;
#pragma unroll
  for (int s = 1; s < 64; s <<= 1) mx = fmaxf(mx, __shfl_xor(mx, s));
  float se = expf(yg - mx);
#pragma unroll
  for (int s = 1; s < 64; s <<= 1) se += __shfl_xor(se, s);
  float d = x_pred - ym;
  float lk = -0.5f * d * d - 66.0f * ysg - 58.812066f;
  float ts = expf(yg - mx + lk);
#pragma unroll
  for (int s = 1; s < 64; s <<= 1) ts += __shfl_xor(ts, s);
  float prob = ts / se;

  if (lane == 0) {
    out[rid] = x_pred;
    out[(size_t)Mdim * Tdim + rid] = prob;
  }
}

__device__ __host__ inline unsigned short bf16_trunc(float x) {
  union { float f; uint32_t u; } c; c.f = x;
  return (unsigned short)(c.u >> 16);
}
__device__ __host__ inline float bf16_tof(unsigned short s) {
  union { float f; uint32_t u; } c; c.u = ((uint32_t)s) << 16;
  return c.f;
}

// Prep: pack B-frags (bf16x3, frag-linear), WZ, biases, FC table.
// Gate map: local g = ul*4+ty, gd = ty*256 + ug*4 + ul.
// Frag k map (A and B identical): k = kt*32 + (lane>>4)*8 + e.
__global__ void vfpg_prep(const float* __restrict__ Wih0, const float* __restrict__ Whh0,
                          const float* __restrict__ Wih1, const float* __restrict__ Whh1,
                          const float* __restrict__ fcW, const float* __restrict__ bih0,
                          const float* __restrict__ bhh0, const float* __restrict__ bih1,
                          const float* __restrict__ bhh1, float* __restrict__ ws) {
  int i0 = blockIdx.x * blockDim.x + threadIdx.x;
  int n = blockDim.x * gridDim.x;
  unsigned short* BF = (unsigned short*)(ws + OFF_BFRAG);
  for (int i = i0; i < 64 * 3 * 8 * 512; i += n) {
    int ug = i / 12288, r = i % 12288;
    int cls = r / 4096, r2 = r % 4096;
    int kt = r2 >> 9, pos = r2 & 511;
    int l = pos >> 3, e = pos & 7;
    int n16 = l & 15, lg = l >> 4;
    int k = kt * 32 + lg * 8 + e;
    int ul = n16 >> 2, ty = n16 & 3;
    int gd = ty * 256 + ug * 4 + ul;
    const float* W = (cls == 0) ? Whh0 : ((cls == 1) ? Wih1 : Whh1);
    float w = W[gd * 256 + k];
    unsigned short s0 = bf16_trunc(w);
    float r1 = w - bf16_tof(s0);
    unsigned short s1 = bf16_trunc(r1);
    unsigned short s2 = bf16_trunc(r1 - bf16_tof(s1));
    size_t base = ((size_t)(ug * 3 + cls) * 8 + kt) * (3 * 512) + pos;
    BF[base] = s0;
    BF[base + 512] = s1;
    BF[base + 1024] = s2;
  }
  for (int i = i0; i < 64 * 256; i += n) {   // WZ [ug][k16][g16] fp32
    int ug = i >> 8, k = (i >> 4) & 15, g = i & 15;
    int gd = (g & 3) * 256 + ug * 4 + (g >> 2);
    ws[OFF_WZ + i] = Wih0[gd * INdim + k];
  }
  for (int i = i0; i < 64 * 32; i += n) {    // biases [ug][layer2][g16]
    int ug = i >> 5, r = i & 31, g = r & 15;
    int gd = (g & 3) * 256 + ug * 4 + (g >> 2);
    ws[OFF_BB + i] = (r < 16) ? (bih0[gd] + bhh0[gd]) : (bih1[gd] + bhh1[gd]);
  }
  float4* wfcp = (float4*)(ws + OFF_WFCP);
  for (int o = i0; o < 256 * 64; o += n) {
    int k = o >> 6, c = o & 63;
    wfcp[o] = make_float4(fcW[c * Hdim + k], fcW[(64 + c) * Hdim + k],
                          fcW[(128 + c) * Hdim + k], 0.0f);
  }
}

__device__ inline void cell1s(float gi, float gf, float gg, float go, float cold,
                              float* cn, float* hn) {
  float si = sigm_fast(gi), sf = sigm_fast(gf);
  float tg = fmaf(2.0f, sigm_fast(2.0f * gg), -1.0f);
  float so = sigm_fast(go);
  float cc = fmaf(sf, cold, si * tg);
  *cn = cc;
  *hn = so * fmaf(2.0f, sigm_fast(2.0f * cc), -1.0f);
}

#define GBS 17   // gbuf row stride (bank-conflict-free)

// Launch t: layer0 step t + layer1 step t-1. MODE 0: t=0; 1: 1..63; 2: t=64.
// Block (rg = bid&7 -> XCD-local h panels, ug = bid>>3). 256 thr, 4 waves x 4 mtiles.
template <int MODE>
__launch_bounds__(256, 2)
__global__ void vfpg_step(const float* __restrict__ z, const float* __restrict__ ws,
                          float* __restrict__ wsm, int t) {
  __shared__ unsigned short lB[3 * 8 * 2 * 512];   // 48 KB: splits 0,1
  __shared__ float gbuf[256 * GBS];                // 17 KB
  __shared__ float lz[256];
  __shared__ float lbias[32];

  const int tid = threadIdx.x;
  const int rg = blockIdx.x & 7, ug = blockIdx.x >> 3;
  const int mb = rg * 256;
  const int lane = tid & 63, wid = tid >> 6;

  // cooperative loads
  {
    const unsigned short* BG = (const unsigned short*)(ws + OFF_BFRAG) + (size_t)ug * BFRAG_US;
    s16x8* dst = (s16x8*)lB;
    for (int i = tid; i < 3 * 8 * 2 * 64; i += 256) {   // 3072 vec8
      int ck = i >> 7, sp = (i >> 6) & 1, v = i & 63;   // ck = cls*8+kt
      dst[i] = *(const s16x8*)(BG + ((size_t)ck * 3 + sp) * 512 + v * 8);
    }
    if (tid < 64) ((float4*)lz)[tid] = ((const float4*)(ws + OFF_WZ + ug * 256))[tid];
    if (tid < 32) lbias[tid] = ws[OFF_BB + ug * 32 + tid];
  }
  __syncthreads();

  f32x4 aL0[4], aL1[4];
#pragma unroll
  for (int i = 0; i < 4; i++) {
    aL0[i] = (f32x4)0.0f;
    aL1[i] = (f32x4)0.0f;
  }

  if (MODE >= 1) {
    const unsigned short* p0 = (const unsigned short*)(ws + OFF_H0P) +
                               ((size_t)((t - 1) & 1) * 8 + rg) * PANEL_US;
    const unsigned short* p1 = (const unsigned short*)(ws + OFF_RINGF) +
                               ((size_t)((t - 2) & 15) * 8 + rg) * PANEL_US;
    const unsigned short* BG2 = (const unsigned short*)(ws + OFF_BFRAG) + (size_t)ug * BFRAG_US;
    const bool doH1 = (t >= 2);
    const s16x8* pLB = (const s16x8*)lB;

#pragma unroll 1
    for (int kt = 0; kt < 8; kt++) {
      s16x8 bL0s0, bL0s1, bL0s2, bIs0, bIs1, bIs2, bHs0, bHs1, bHs2;
      if (MODE == 1) {
        bL0s0 = pLB[((0 * 8 + kt) * 2 + 0) * 64 + lane];
        bL0s1 = pLB[((0 * 8 + kt) * 2 + 1) * 64 + lane];
        bL0s2 = *(const s16x8*)(BG2 + ((size_t)(0 * 8 + kt) * 3 + 2) * 512 + lane * 8);
      }
      bIs0 = pLB[((1 * 8 + kt) * 2 + 0) * 64 + lane];
      bIs1 = pLB[((1 * 8 + kt) * 2 + 1) * 64 + lane];
      bIs2 = *(const s16x8*)(BG2 + ((size_t)(1 * 8 + kt) * 3 + 2) * 512 + lane * 8);
      if (doH1) {
        bHs0 = pLB[((2 * 8 + kt) * 2 + 0) * 64 + lane];
        bHs1 = pLB[((2 * 8 + kt) * 2 + 1) * 64 + lane];
        bHs2 = *(const s16x8*)(BG2 + ((size_t)(2 * 8 + kt) * 3 + 2) * 512 + lane * 8);
      }
#pragma unroll
      for (int i = 0; i < 4; i++) {
        int mt = wid * 4 + i;
        size_t f0 = ((size_t)(0 * 16 + mt) * 8 + kt) * 512 + lane * 8;
        size_t f1 = ((size_t)(1 * 16 + mt) * 8 + kt) * 512 + lane * 8;
        size_t f2 = ((size_t)(2 * 16 + mt) * 8 + kt) * 512 + lane * 8;
        s16x8 a0 = *(const s16x8*)(p0 + f0);
        s16x8 a1 = *(const s16x8*)(p0 + f1);
        s16x8 a2 = *(const s16x8*)(p0 + f2);
        if (MODE == 1) {
          aL0[i] = __builtin_amdgcn_mfma_f32_16x16x32_bf16(a0, bL0s0, aL0[i], 0, 0, 0);
          aL0[i] = __builtin_amdgcn_mfma_f32_16x16x32_bf16(a0, bL0s1, aL0[i], 0, 0, 0);
          aL0[i] = __builtin_amdgcn_mfma_f32_16x16x32_bf16(a1, bL0s0, aL0[i], 0, 0, 0);
          aL0[i] = __builtin_amdgcn_mfma_f32_16x16x32_bf16(a1, bL0s1, aL0[i], 0, 0, 0);
          aL0[i] = __builtin_amdgcn_mfma_f32_16x16x32_bf16(a0, bL0s2, aL0[i], 0, 0, 0);
          aL0[i] = __builtin_amdgcn_mfma_f32_16x16x32_bf16(a2, bL0s0, aL0[i], 0, 0, 0);
        }
        aL1[i] = __builtin_amdgcn_mfma_f32_16x16x32_bf16(a0, bIs0, aL1[i], 0, 0, 0);
        aL1[i] = __builtin_amdgcn_mfma_f32_16x16x32_bf16(a0, bIs1, aL1[i], 0, 0, 0);
        aL1[i] = __builtin_amdgcn_mfma_f32_16x16x32_bf16(a1, bIs0, aL1[i], 0, 0, 0);
        aL1[i] = __builtin_amdgcn_mfma_f32_16x16x32_bf16(a1, bIs1, aL1[i], 0, 0, 0);
        aL1[i] = __builtin_amdgcn_mfma_f32_16x16x32_bf16(a0, bIs2, aL1[i], 0, 0, 0);
        aL1[i] = __builtin_amdgcn_mfma_f32_16x16x32_bf16(a2, bIs0, aL1[i], 0, 0, 0);
        if (doH1) {
          s16x8 c0 = *(const s16x8*)(p1 + f0);
          s16x8 c1 = *(const s16x8*)(p1 + f1);
          s16x8 c2 = *(const s16x8*)(p1 + f2);
          aL1[i] = __builtin_amdgcn_mfma_f32_16x16x32_bf16(c0, bHs0, aL1[i], 0, 0, 0);
          aL1[i] = __builtin_amdgcn_mfma_f32_16x16x32_bf16(c0, bHs1, aL1[i], 0, 0, 0);
          aL1[i] = __builtin_amdgcn_mfma_f32_16x16x32_bf16(c1, bHs0, aL1[i], 0, 0, 0);
          aL1[i] = __builtin_amdgcn_mfma_f32_16x16x32_bf16(c1, bHs1, aL1[i], 0, 0, 0);
          aL1[i] = __builtin_amdgcn_mfma_f32_16x16x32_bf16(c0, bHs2, aL1[i], 0, 0, 0);
          aL1[i] = __builtin_amdgcn_mfma_f32_16x16x32_bf16(c2, bHs0, aL1[i], 0, 0, 0);
        }
      }
    }
  }

  float* c0w = wsm + OFF_C0;
  float* c1w = wsm + OFF_C1;
  const int mloc = tid;
  const int m = mb + mloc;
  const int mtc = mloc >> 4, mrowc = mloc & 15;

  // ================= L0 phase =================
  if (MODE <= 1) {
    if (MODE == 1) {
      int col = lane & 15, rb2 = (lane >> 4) * 4;
#pragma unroll
      for (int i = 0; i < 4; i++) {
        int mt = wid * 4 + i;
#pragma unroll
        for (int j = 0; j < 4; j++)
          gbuf[(mt * 16 + rb2 + j) * GBS + col] = aL0[i][j];
      }
    }
    __syncthreads();
    // cell update: thread = row
    float zr[16];
#pragma unroll
    for (int f4 = 0; f4 < 4; f4++)
      *(float4*)&zr[f4 * 4] = *(const float4*)&z[(size_t)m * 1024 + t * 16 + f4 * 4];
    float g16[16];
#pragma unroll
    for (int gg = 0; gg < 16; gg++)
      g16[gg] = lbias[gg] + ((MODE == 1) ? gbuf[mloc * GBS + gg] : 0.0f);
#pragma unroll
    for (int f = 0; f < 16; f++) {
      float zv = zr[f];
      float4 w0 = *(const float4*)&lz[f * 16 + 0];
      float4 w1 = *(const float4*)&lz[f * 16 + 4];
      float4 w2 = *(const float4*)&lz[f * 16 + 8];
      float4 w3 = *(const float4*)&lz[f * 16 + 12];
      g16[0] = fmaf(zv, w0.x, g16[0]);  g16[1] = fmaf(zv, w0.y, g16[1]);
      g16[2] = fmaf(zv, w0.z, g16[2]);  g16[3] = fmaf(zv, w0.w, g16[3]);
      g16[4] = fmaf(zv, w1.x, g16[4]);  g16[5] = fmaf(zv, w1.y, g16[5]);
      g16[6] = fmaf(zv, w1.z, g16[6]);  g16[7] = fmaf(zv, w1.w, g16[7]);
      g16[8] = fmaf(zv, w2.x, g16[8]);  g16[9] = fmaf(zv, w2.y, g16[9]);
      g16[10] = fmaf(zv, w2.z, g16[10]); g16[11] = fmaf(zv, w2.w, g16[11]);
      g16[12] = fmaf(zv, w3.x, g16[12]); g16[13] = fmaf(zv, w3.y, g16[13]);
      g16[14] = fmaf(zv, w3.z, g16[14]); g16[15] = fmaf(zv, w3.w, g16[15]);
    }
    unsigned short* wp = (unsigned short*)(wsm + OFF_H0P) +
                         ((size_t)(t & 1) * 8 + rg) * PANEL_US;
#pragma unroll
    for (int ul = 0; ul < 4; ul++) {
      int u = ug * 4 + ul;
      size_t cidx = (size_t)u * 2048 + m;
      float cold = (MODE == 1) ? c0w[cidx] : 0.0f;
      float cn, hn;
      cell1s(g16[ul * 4 + 0], g16[ul * 4 + 1], g16[ul * 4 + 2], g16[ul * 4 + 3], cold, &cn, &hn);
      c0w[cidx] = cn;
      int kt = u >> 5, kk = u & 31, lg = kk >> 3, e = kk & 7, lw = lg * 16 + mrowc;
      unsigned short s0 = bf16_trunc(hn);
      float r1 = hn - bf16_tof(s0);
      unsigned short s1 = bf16_trunc(r1);
      unsigned short s2 = bf16_trunc(r1 - bf16_tof(s1));
      size_t fo = ((size_t)(0 * 16 + mtc) * 8 + kt) * 512 + lw * 8 + e;
      wp[fo] = s0;
      wp[fo + 16 * 8 * 512] = s1;        // sp=1
      wp[fo + 2 * 16 * 8 * 512] = s2;    // sp=2
    }
    __syncthreads();
  }

  // ================= L1 phase =================
  if (MODE >= 1) {
    {
      int col = lane & 15, rb2 = (lane >> 4) * 4;
#pragma unroll
      for (int i = 0; i < 4; i++) {
        int mt = wid * 4 + i;
#pragma unroll
        for (int j = 0; j < 4; j++)
          gbuf[(mt * 16 + rb2 + j) * GBS + col] = aL1[i][j];
      }
    }
    __syncthreads();
    int slot = (t - 1) & 15;
    unsigned short* rp = (unsigned short*)(wsm + OFF_RINGF) +
                         ((size_t)slot * 8 + rg) * PANEL_US;
    float* r2 = wsm + OFF_RING2 + (size_t)slot * HSLAB;
    float h4[4];
#pragma unroll
    for (int ul = 0; ul < 4; ul++) {
      int gg = ul * 4;
      float gi = lbias[16 + gg + 0] + gbuf[mloc * GBS + gg + 0];
      float gf = lbias[16 + gg + 1] + gbuf[mloc * GBS + gg + 1];
      float gt = lbias[16 + gg + 2] + gbuf[mloc * GBS + gg + 2];
      float go = lbias[16 + gg + 3] + gbuf[mloc * GBS + gg + 3];
      int u = ug * 4 + ul;
      size_t cidx = (size_t)u * 2048 + m;
      float cold = (t >= 2) ? c1w[cidx] : 0.0f;
      float cn, hn;
      cell1s(gi, gf, gt, go, cold, &cn, &hn);
      c1w[cidx] = cn;
      h4[ul] = hn;
      int kt = u >> 5, kk = u & 31, lg = kk >> 3, e = kk & 7, lw = lg * 16 + mrowc;
      unsigned short s0 = bf16_trunc(hn);
      float r1v = hn - bf16_tof(s0);
      unsigned short s1 = bf16_trunc(r1v);
      unsigned short s2 = bf16_trunc(r1v - bf16_tof(s1));
      size_t fo = ((size_t)(0 * 16 + mtc) * 8 + kt) * 512 + lw * 8 + e;
      rp[fo] = s0;
      rp[fo + 16 * 8 * 512] = s1;
      rp[fo + 2 * 16 * 8 * 512] = s2;
    }
    *(float4*)&r2[(size_t)m * 256 + ug * 4] = make_float4(h4[0], h4[1], h4[2], h4[3]);
  }
}

// Head: FC + MDN for 16 slots x 2048 rows; wave = 8 rows; b128 LDS reads.
__launch_bounds__(512, 2)
__global__ void vfpg_head(const float* __restrict__ ws, const float* __restrict__ fcb,
                          float* __restrict__ out, int tbase,
                          uint32_t k1a, uint32_t k1b, uint32_t k2a, uint32_t k2b) {
  __shared__ __align__(16) float hsw[8][8][Hdim];   // 64 KB
  const int tid = threadIdx.x;
  const int lane = tid & 63, wid = tid >> 6;
  const int rb8 = blockIdx.x * 8 + wid;
  const int slot = rb8 >> 8;
  const int mbase = (rb8 & 255) * 8;

  const float* r2 = ws + OFF_RING2 + (size_t)slot * HSLAB + (size_t)mbase * 256;
  const float4* WFCP = (const float4*)(ws + OFF_WFCP);

#pragma unroll
  for (int rr = 0; rr < 8; rr++)
    *(float4*)&hsw[wid][rr][lane * 4] = *(const float4*)&r2[rr * 256 + lane * 4];
  __builtin_amdgcn_s_waitcnt(0);

  float yg[8], ys[8], ym[8];
#pragma unroll
  for (int rr = 0; rr < 8; rr++) {
    yg[rr] = fcb[lane]; ys[rr] = fcb[64 + lane]; ym[rr] = fcb[128 + lane];
  }
#pragma unroll 2
  for (int k4 = 0; k4 < 64; k4++) {
    float4 h4[8];
#pragma unroll
    for (int rr = 0; rr < 8; rr++) h4[rr] = *(const float4*)&hsw[wid][rr][k4 * 4];
#pragma unroll
    for (int j = 0; j < 4; j++) {
      float4 w = WFCP[(k4 * 4 + j) * 64 + lane];
#pragma unroll
      for (int rr = 0; rr < 8; rr++) {
        float hv = (&h4[rr].x)[j];
        yg[rr] = fmaf(hv, w.x, yg[rr]);
        ys[rr] = fmaf(hv, w.y, ys[rr]);
        ym[rr] = fmaf(hv, w.z, ym[rr]);
      }
    }
  }
  int tt = tbase + slot;
#pragma unroll 1
  for (int rr = 0; rr < 8; rr++) {
    uint32_t rid = (uint32_t)(mbase + rr) * Tdim + (uint32_t)tt;
    mdn_head(yg[rr], ys[rr], ym[rr], lane, rid, k1a, k1b, k2a, k2b, out);
  }
}

extern "C" void kernel_launch(void* const* d_in, const int* in_sizes, int n_in,
                              void* d_out, int out_size, void* d_ws, size_t ws_size,
                              hipStream_t stream) {
  const float* z    = (const float*)d_in[0];
  const float* Wih0 = (const float*)d_in[1];
  const float* Whh0 = (const float*)d_in[2];
  const float* bih0 = (const float*)d_in[3];
  const float* bhh0 = (const float*)d_in[4];
  const float* Wih1 = (const float*)d_in[5];
  const float* Whh1 = (const float*)d_in[6];
  const float* bih1 = (const float*)d_in[7];
  const float* bhh1 = (const float*)d_in[8];
  const float* fcW  = (const float*)d_in[9];
  const float* fcb  = (const float*)d_in[10];
  float* ws = (float*)d_ws;
  float* out = (float*)d_out;

  if (ws_size < (size_t)WS_TOT * sizeof(float)) return;  // ~99.4 MB (<137.7 proven)

  vfpg_prep<<<dim3(512), dim3(256), 0, stream>>>(
      Wih0, Whh0, Wih1, Whh1, fcW, bih0, bhh0, bih1, bhh1, ws);

  uint32_t k1a, k1b, k2a, k2b;
  tf2x32(0u, 42u, 0u, 0u, &k1a, &k1b);
  tf2x32(0u, 42u, 0u, 1u, &k2a, &k2b);

  vfpg_step<0><<<dim3(512), dim3(256), 0, stream>>>(z, ws, ws, 0);
  for (int t = 1; t <= 63; t++) {
    vfpg_step<1><<<dim3(512), dim3(256), 0, stream>>>(z, ws, ws, t);
    if (t == 16 || t == 32 || t == 48) {
      vfpg_head<<<dim3(512), dim3(512), 0, stream>>>(ws, fcb, out, t - 16,
                                                     k1a, k1b, k2a, k2b);
    }
  }
  vfpg_step<2><<<dim3(512), dim3(256), 0, stream>>>(z, ws, ws, 64);
  vfpg_head<<<dim3(512), dim3(512), 0, stream>>>(ws, fcb, out, 48, k1a, k1b, k2a, k2b);
}

// Round 13
// 2080.911 us; speedup vs baseline: 3.7875x; 1.6684x over previous
//
#include <hip/hip_runtime.h>
#include <stdint.h>
#include <stddef.h>

// Problem dims
#define Mdim 2048
#define Tdim 64
#define INdim 16
#define Hdim 256
#define NCdim 64
#define NUG 64
#define HSLAB (256 * 2048)
#define RSLOTS 16

typedef __attribute__((ext_vector_type(8))) short s16x8;
typedef __attribute__((ext_vector_type(4))) float f32x4;

// Panel (per tbuf/slot, per rg): [sp3][mt16][kt8][512] bf16  -> 196608 ushorts
#define PANEL_US (3 * 16 * 8 * 512)
#define SPOFF 65536   // 16*8*512, split stride in ushorts
// BFRAG per ug: [cls3][kt8][sp3][512] bf16 -> 36864 ushorts
#define BFRAG_US (3 * 8 * 3 * 512)

// ws float offsets
#define OFF_BFRAG 0                                    // 64 * 36864 us = 1179648 fl
#define OFF_WZ    1179648                              // [64][16 k][16 g] fp32
#define OFF_BB    (OFF_WZ + 64 * 256)                  // [64][32]
#define OFF_WFCP  (OFF_BB + 64 * 32)                   // [256][64] float4
#define OFF_H0P   (OFF_WFCP + 256 * 64 * 4)            // [2 tbuf][8 rg] panels: 1572864 fl
#define OFF_C0    (OFF_H0P + 1572864)
#define OFF_C1    (OFF_C0 + HSLAB)
#define OFF_RINGF (OFF_C1 + HSLAB)                     // [16 slot][8 rg] panels: 12582912 fl
#define OFF_RING2 (OFF_RINGF + 12582912)               // fp32 [16][2048 m][256 u]
#define WS_TOT    (OFF_RING2 + RSLOTS * HSLAB)         // 24856576 fl = 99.4 MB

#define ROTL32(v, s) (((v) << (s)) | ((v) >> (32 - (s))))

__host__ __device__ inline void tf2x32(uint32_t k0, uint32_t k1, uint32_t x0, uint32_t x1,
                                       uint32_t* o0, uint32_t* o1) {
  uint32_t ks2 = k0 ^ k1 ^ 0x1BD11BDAu;
  x0 += k0; x1 += k1;
  x0 += x1; x1 = ROTL32(x1, 13); x1 ^= x0;
  x0 += x1; x1 = ROTL32(x1, 15); x1 ^= x0;
  x0 += x1; x1 = ROTL32(x1, 26); x1 ^= x0;
  x0 += x1; x1 = ROTL32(x1, 6);  x1 ^= x0;
  x0 += k1; x1 += ks2 + 1u;
  x0 += x1; x1 = ROTL32(x1, 17); x1 ^= x0;
  x0 += x1; x1 = ROTL32(x1, 29); x1 ^= x0;
  x0 += x1; x1 = ROTL32(x1, 16); x1 ^= x0;
  x0 += x1; x1 = ROTL32(x1, 24); x1 ^= x0;
  x0 += ks2; x1 += k0 + 2u;
  x0 += x1; x1 = ROTL32(x1, 13); x1 ^= x0;
  x0 += x1; x1 = ROTL32(x1, 15); x1 ^= x0;
  x0 += x1; x1 = ROTL32(x1, 26); x1 ^= x0;
  x0 += x1; x1 = ROTL32(x1, 6);  x1 ^= x0;
  x0 += k0; x1 += k1 + 3u;
  x0 += x1; x1 = ROTL32(x1, 17); x1 ^= x0;
  x0 += x1; x1 = ROTL32(x1, 29); x1 ^= x0;
  x0 += x1; x1 = ROTL32(x1, 16); x1 ^= x0;
  x0 += x1; x1 = ROTL32(x1, 24); x1 ^= x0;
  x0 += k1; x1 += ks2 + 4u;
  x0 += x1; x1 = ROTL32(x1, 13); x1 ^= x0;
  x0 += x1; x1 = ROTL32(x1, 15); x1 ^= x0;
  x0 += x1; x1 = ROTL32(x1, 26); x1 ^= x0;
  x0 += x1; x1 = ROTL32(x1, 6);  x1 ^= x0;
  x0 += ks2; x1 += k0 + 5u;
  *o0 = x0; *o1 = x1;
}

__device__ inline uint32_t random_bits32(uint32_t ka, uint32_t kb, uint32_t p) {
  uint32_t a, b;
  tf2x32(ka, kb, 0u, p, &a, &b);
  return a ^ b;
}

__device__ inline float bits_to_u01(uint32_t bits) {
  return __uint_as_float((bits >> 9) | 0x3f800000u) - 1.0f;
}

__device__ inline float sigm_fast(float x) { return 1.0f / (1.0f + __expf(-x)); }

__device__ inline float erfinv_f32(float x) {
  float w = -log1pf(-x * x);
  float p;
  if (w < 5.0f) {
    w -= 2.5f;
    p = 2.81022636e-08f;
    p = fmaf(p, w, 3.43273939e-07f);
    p = fmaf(p, w, -3.5233877e-06f);
    p = fmaf(p, w, -4.39150654e-06f);
    p = fmaf(p, w, 0.00021858087f);
    p = fmaf(p, w, -0.00125372503f);
    p = fmaf(p, w, -0.00417768164f);
    p = fmaf(p, w, 0.246640727f);
    p = fmaf(p, w, 1.50140941f);
  } else {
    w = sqrtf(w) - 3.0f;
    p = -0.000200214257f;
    p = fmaf(p, w, 0.000100950558f);
    p = fmaf(p, w, 0.00134934322f);
    p = fmaf(p, w, -0.00367342844f);
    p = fmaf(p, w, 0.00573950773f);
    p = fmaf(p, w, -0.0076224613f);
    p = fmaf(p, w, 0.00943887047f);
    p = fmaf(p, w, 1.00167406f);
    p = fmaf(p, w, 2.83297682f);
  }
  return p * x;
}

__device__ inline void mdn_head(float yg, float ysg, float ym, int lane, uint32_t rid,
                                uint32_t k1a, uint32_t k1b, uint32_t k2a, uint32_t k2b,
                                float* __restrict__ out) {
  uint32_t pp = rid * (uint32_t)NCdim + (uint32_t)lane;
  uint32_t bits = random_bits32(k1a, k1b, pp);
  float u01 = bits_to_u01(bits);
  const float tinyf = 1.17549435e-38f;
  float uu = fmaxf(tinyf, u01 + tinyf);
  float gum = -logf(-logf(uu));
  float val = gum + yg;
  int idx = lane;
#pragma unroll
  for (int s = 1; s < 64; s <<= 1) {
    float ov = __shfl_xor(val, s);
    int oi = __shfl_xor(idx, s);
    if (ov > val || (ov == val && oi < idx)) { val = ov; idx = oi; }
  }
  float mu_sel = __shfl(ym, idx);
  float s_sel = __shfl(ysg, idx);

  uint32_t ebits = random_bits32(k2a, k2b, rid);
  float ue = bits_to_u01(ebits);
  const float lo = __uint_as_float(0xBF7FFFFFu);
  float un2 = fmaxf(lo, ue * 2.0f + lo);
  float eps = 1.41421356f * erfinv_f32(un2);

  float x_pred = mu_sel + expf(s_sel) * eps;

  float mx = yg;
#pragma unroll
  for (int s = 1; s < 64; s <<= 1) mx = fmaxf(mx, __shfl_xor(mx, s));
  float se = expf(yg - mx);
#pragma unroll
  for (int s = 1; s < 64; s <<= 1) se += __shfl_xor(se, s);
  float d = x_pred - ym;
  float lk = -0.5f * d * d - 66.0f * ysg - 58.812066f;
  float ts = expf(yg - mx + lk);
#pragma unroll
  for (int s = 1; s < 64; s <<= 1) ts += __shfl_xor(ts, s);
  float prob = ts / se;

  if (lane == 0) {
    out[rid] = x_pred;
    out[(size_t)Mdim * Tdim + rid] = prob;
  }
}

__device__ __host__ inline unsigned short bf16_trunc(float x) {
  union { float f; uint32_t u; } c; c.f = x;
  return (unsigned short)(c.u >> 16);
}
__device__ __host__ inline float bf16_tof(unsigned short s) {
  union { float f; uint32_t u; } c; c.u = ((uint32_t)s) << 16;
  return c.f;
}

// Prep: pack B-frags (bf16x3, frag-linear), WZ, biases, FC table. (unchanged from R12)
__global__ void vfpg_prep(const float* __restrict__ Wih0, const float* __restrict__ Whh0,
                          const float* __restrict__ Wih1, const float* __restrict__ Whh1,
                          const float* __restrict__ fcW, const float* __restrict__ bih0,
                          const float* __restrict__ bhh0, const float* __restrict__ bih1,
                          const float* __restrict__ bhh1, float* __restrict__ ws) {
  int i0 = blockIdx.x * blockDim.x + threadIdx.x;
  int n = blockDim.x * gridDim.x;
  unsigned short* BF = (unsigned short*)(ws + OFF_BFRAG);
  for (int i = i0; i < 64 * 3 * 8 * 512; i += n) {
    int ug = i / 12288, r = i % 12288;
    int cls = r / 4096, r2 = r % 4096;
    int kt = r2 >> 9, pos = r2 & 511;
    int l = pos >> 3, e = pos & 7;
    int n16 = l & 15, lg = l >> 4;
    int k = kt * 32 + lg * 8 + e;
    int ul = n16 >> 2, ty = n16 & 3;
    int gd = ty * 256 + ug * 4 + ul;
    const float* W = (cls == 0) ? Whh0 : ((cls == 1) ? Wih1 : Whh1);
    float w = W[gd * 256 + k];
    unsigned short s0 = bf16_trunc(w);
    float r1 = w - bf16_tof(s0);
    unsigned short s1 = bf16_trunc(r1);
    unsigned short s2 = bf16_trunc(r1 - bf16_tof(s1));
    size_t base = ((size_t)(ug * 3 + cls) * 8 + kt) * (3 * 512) + pos;
    BF[base] = s0;
    BF[base + 512] = s1;
    BF[base + 1024] = s2;
  }
  for (int i = i0; i < 64 * 256; i += n) {
    int ug = i >> 8, k = (i >> 4) & 15, g = i & 15;
    int gd = (g & 3) * 256 + ug * 4 + (g >> 2);
    ws[OFF_WZ + i] = Wih0[gd * INdim + k];
  }
  for (int i = i0; i < 64 * 32; i += n) {
    int ug = i >> 5, r = i & 31, g = r & 15;
    int gd = (g & 3) * 256 + ug * 4 + (g >> 2);
    ws[OFF_BB + i] = (r < 16) ? (bih0[gd] + bhh0[gd]) : (bih1[gd] + bhh1[gd]);
  }
  float4* wfcp = (float4*)(ws + OFF_WFCP);
  for (int o = i0; o < 256 * 64; o += n) {
    int k = o >> 6, c = o & 63;
    wfcp[o] = make_float4(fcW[c * Hdim + k], fcW[(64 + c) * Hdim + k],
                          fcW[(128 + c) * Hdim + k], 0.0f);
  }
}

__device__ inline void cell1s(float gi, float gf, float gg, float go, float cold,
                              float* cn, float* hn) {
  float si = sigm_fast(gi), sf = sigm_fast(gf);
  float tg = fmaf(2.0f, sigm_fast(2.0f * gg), -1.0f);
  float so = sigm_fast(go);
  float cc = fmaf(sf, cold, si * tg);
  *cn = cc;
  *hn = so * fmaf(2.0f, sigm_fast(2.0f * cc), -1.0f);
}

#define GBS 17   // gbuf row stride

// Launch t: layer0 step t + layer1 step t-1. MODE 0: t=0; 1: 1..63; 2: t=64.
// Block (rg = bid&7 -> XCD-local panels, ug = bid>>3). 256 thr, 4 waves x 4 mtiles.
template <int MODE>
__launch_bounds__(256, 3)
__global__ void vfpg_step(const float* __restrict__ z, const float* __restrict__ ws,
                          float* __restrict__ wsm, int t) {
  __shared__ unsigned short lB[2 * 8 * 2 * 512];   // 32 KB: cls{L0,IH1} x splits{0,1}
  __shared__ float gbuf[256 * GBS];                // 17 KB
  __shared__ float lz[256];
  __shared__ float lbias[32];

  const int tid = threadIdx.x;
  const int rg = blockIdx.x & 7, ug = blockIdx.x >> 3;
  const int mb = rg * 256;
  const int lane = tid & 63, wid = tid >> 6;

  // cooperative loads
  {
    const unsigned short* BG = (const unsigned short*)(ws + OFF_BFRAG) + (size_t)ug * BFRAG_US;
    s16x8* dst = (s16x8*)lB;
    for (int i = tid; i < 2 * 8 * 2 * 64; i += 256) {   // 2048 vec8
      int ck = i >> 7, sp = (i >> 6) & 1, v = i & 63;   // ck = cls*8+kt, cls in {0,1}
      dst[i] = *(const s16x8*)(BG + ((size_t)ck * 3 + sp) * 512 + v * 8);
    }
    if (tid < 64) ((float4*)lz)[tid] = ((const float4*)(ws + OFF_WZ + ug * 256))[tid];
    if (tid < 32) lbias[tid] = ws[OFF_BB + ug * 32 + tid];
  }
  __syncthreads();

  f32x4 aL0[4], aL1[4];
#pragma unroll
  for (int i = 0; i < 4; i++) {
    aL0[i] = (f32x4)0.0f;
    aL1[i] = (f32x4)0.0f;
  }

  if (MODE >= 1) {
    const unsigned short* p0 = (const unsigned short*)(ws + OFF_H0P) +
                               ((size_t)((t - 1) & 1) * 8 + rg) * PANEL_US;
    const unsigned short* p1 = (const unsigned short*)(ws + OFF_RINGF) +
                               ((size_t)((t - 2) & 15) * 8 + rg) * PANEL_US;
    const unsigned short* BG2 = (const unsigned short*)(ws + OFF_BFRAG) + (size_t)ug * BFRAG_US;
    const bool doH1 = (t >= 2);
    const s16x8* pLB = (const s16x8*)lB;

    s16x8 Ab0[6], Ab1[6];
    {  // initial prefetch (kt=0, i=0)
      size_t fb = ((size_t)(wid * 4) * 8 + 0) * 512 + lane * 8;
      Ab0[0] = *(const s16x8*)(p0 + fb);
      Ab0[1] = *(const s16x8*)(p0 + fb + SPOFF);
      Ab0[2] = *(const s16x8*)(p0 + fb + 2 * SPOFF);
      if (doH1) {
        Ab0[3] = *(const s16x8*)(p1 + fb);
        Ab0[4] = *(const s16x8*)(p1 + fb + SPOFF);
        Ab0[5] = *(const s16x8*)(p1 + fb + 2 * SPOFF);
      }
    }

#pragma unroll 1
    for (int kt = 0; kt < 8; kt++) {
      s16x8 bL0s0, bL0s1, bL0s2, bIs0, bIs1, bIs2, bHs0, bHs1, bHs2;
      if (MODE == 1) {
        bL0s0 = pLB[(kt * 2 + 0) * 64 + lane];
        bL0s1 = pLB[(kt * 2 + 1) * 64 + lane];
        bL0s2 = *(const s16x8*)(BG2 + ((size_t)kt * 3 + 2) * 512 + lane * 8);
      }
      bIs0 = pLB[((8 + kt) * 2 + 0) * 64 + lane];
      bIs1 = pLB[((8 + kt) * 2 + 1) * 64 + lane];
      bIs2 = *(const s16x8*)(BG2 + ((size_t)(8 + kt) * 3 + 2) * 512 + lane * 8);
      if (doH1) {
        bHs0 = *(const s16x8*)(BG2 + ((size_t)(16 + kt) * 3 + 0) * 512 + lane * 8);
        bHs1 = *(const s16x8*)(BG2 + ((size_t)(16 + kt) * 3 + 1) * 512 + lane * 8);
        bHs2 = *(const s16x8*)(BG2 + ((size_t)(16 + kt) * 3 + 2) * 512 + lane * 8);
      }
#pragma unroll
      for (int i = 0; i < 4; i++) {
        s16x8* cur = (i & 1) ? Ab1 : Ab0;
        s16x8* nxt = (i & 1) ? Ab0 : Ab1;
        int nkt = (i < 3) ? kt : kt + 1;
        int ni = (i < 3) ? (i + 1) : 0;
        if (nkt < 8) {   // prefetch next (kt,i) while this tile computes
          size_t fb = ((size_t)(wid * 4 + ni) * 8 + nkt) * 512 + lane * 8;
          nxt[0] = *(const s16x8*)(p0 + fb);
          nxt[1] = *(const s16x8*)(p0 + fb + SPOFF);
          nxt[2] = *(const s16x8*)(p0 + fb + 2 * SPOFF);
          if (doH1) {
            nxt[3] = *(const s16x8*)(p1 + fb);
            nxt[4] = *(const s16x8*)(p1 + fb + SPOFF);
            nxt[5] = *(const s16x8*)(p1 + fb + 2 * SPOFF);
          }
        }
        s16x8 a0 = cur[0], a1 = cur[1], a2 = cur[2];
        if (MODE == 1) {
          aL0[i] = __builtin_amdgcn_mfma_f32_16x16x32_bf16(a0, bL0s0, aL0[i], 0, 0, 0);
          aL0[i] = __builtin_amdgcn_mfma_f32_16x16x32_bf16(a0, bL0s1, aL0[i], 0, 0, 0);
          aL0[i] = __builtin_amdgcn_mfma_f32_16x16x32_bf16(a1, bL0s0, aL0[i], 0, 0, 0);
          aL0[i] = __builtin_amdgcn_mfma_f32_16x16x32_bf16(a1, bL0s1, aL0[i], 0, 0, 0);
          aL0[i] = __builtin_amdgcn_mfma_f32_16x16x32_bf16(a0, bL0s2, aL0[i], 0, 0, 0);
          aL0[i] = __builtin_amdgcn_mfma_f32_16x16x32_bf16(a2, bL0s0, aL0[i], 0, 0, 0);
        }
        aL1[i] = __builtin_amdgcn_mfma_f32_16x16x32_bf16(a0, bIs0, aL1[i], 0, 0, 0);
        aL1[i] = __builtin_amdgcn_mfma_f32_16x16x32_bf16(a0, bIs1, aL1[i], 0, 0, 0);
        aL1[i] = __builtin_amdgcn_mfma_f32_16x16x32_bf16(a1, bIs0, aL1[i], 0, 0, 0);
        aL1[i] = __builtin_amdgcn_mfma_f32_16x16x32_bf16(a1, bIs1, aL1[i], 0, 0, 0);
        aL1[i] = __builtin_amdgcn_mfma_f32_16x16x32_bf16(a0, bIs2, aL1[i], 0, 0, 0);
        aL1[i] = __builtin_amdgcn_mfma_f32_16x16x32_bf16(a2, bIs0, aL1[i], 0, 0, 0);
        if (doH1) {
          s16x8 c0 = cur[3], c1 = cur[4], c2 = cur[5];
          aL1[i] = __builtin_amdgcn_mfma_f32_16x16x32_bf16(c0, bHs0, aL1[i], 0, 0, 0);
          aL1[i] = __builtin_amdgcn_mfma_f32_16x16x32_bf16(c0, bHs1, aL1[i], 0, 0, 0);
          aL1[i] = __builtin_amdgcn_mfma_f32_16x16x32_bf16(c1, bHs0, aL1[i], 0, 0, 0);
          aL1[i] = __builtin_amdgcn_mfma_f32_16x16x32_bf16(c1, bHs1, aL1[i], 0, 0, 0);
          aL1[i] = __builtin_amdgcn_mfma_f32_16x16x32_bf16(c0, bHs2, aL1[i], 0, 0, 0);
          aL1[i] = __builtin_amdgcn_mfma_f32_16x16x32_bf16(c2, bHs0, aL1[i], 0, 0, 0);
        }
      }
    }
  }

  float* c0w = wsm + OFF_C0;
  float* c1w = wsm + OFF_C1;
  const int mloc = tid;
  const int m = mb + mloc;
  const int mtc = mloc >> 4, mrowc = mloc & 15;
  // packed-write geometry: the 4 units of this ug are 4 consecutive e-slots
  const int ktw = ug >> 3;
  const int lgw = (ug & 7) >> 1;
  const int ebase = (ug * 4) & 7;
  const int lww = lgw * 16 + mrowc;
  const size_t fo = ((size_t)mtc * 8 + ktw) * 512 + lww * 8 + ebase;

  // ================= L0 phase =================
  if (MODE <= 1) {
    if (MODE == 1) {
      int col = lane & 15, rb2 = (lane >> 4) * 4;
#pragma unroll
      for (int i = 0; i < 4; i++) {
        int mt = wid * 4 + i;
#pragma unroll
        for (int j = 0; j < 4; j++)
          gbuf[(mt * 16 + rb2 + j) * GBS + col] = aL0[i][j];
      }
    }
    __syncthreads();
    float zr[16];
#pragma unroll
    for (int f4 = 0; f4 < 4; f4++)
      *(float4*)&zr[f4 * 4] = *(const float4*)&z[(size_t)m * 1024 + t * 16 + f4 * 4];
    float g16[16];
#pragma unroll
    for (int gg = 0; gg < 16; gg++)
      g16[gg] = lbias[gg] + ((MODE == 1) ? gbuf[mloc * GBS + gg] : 0.0f);
#pragma unroll
    for (int f = 0; f < 16; f++) {
      float zv = zr[f];
      float4 w0 = *(const float4*)&lz[f * 16 + 0];
      float4 w1 = *(const float4*)&lz[f * 16 + 4];
      float4 w2 = *(const float4*)&lz[f * 16 + 8];
      float4 w3 = *(const float4*)&lz[f * 16 + 12];
      g16[0] = fmaf(zv, w0.x, g16[0]);  g16[1] = fmaf(zv, w0.y, g16[1]);
      g16[2] = fmaf(zv, w0.z, g16[2]);  g16[3] = fmaf(zv, w0.w, g16[3]);
      g16[4] = fmaf(zv, w1.x, g16[4]);  g16[5] = fmaf(zv, w1.y, g16[5]);
      g16[6] = fmaf(zv, w1.z, g16[6]);  g16[7] = fmaf(zv, w1.w, g16[7]);
      g16[8] = fmaf(zv, w2.x, g16[8]);  g16[9] = fmaf(zv, w2.y, g16[9]);
      g16[10] = fmaf(zv, w2.z, g16[10]); g16[11] = fmaf(zv, w2.w, g16[11]);
      g16[12] = fmaf(zv, w3.x, g16[12]); g16[13] = fmaf(zv, w3.y, g16[13]);
      g16[14] = fmaf(zv, w3.z, g16[14]); g16[15] = fmaf(zv, w3.w, g16[15]);
    }
    unsigned short* wp = (unsigned short*)(wsm + OFF_H0P) +
                         ((size_t)(t & 1) * 8 + rg) * PANEL_US;
    short sp0[4], sp1[4], sp2[4];
#pragma unroll
    for (int ul = 0; ul < 4; ul++) {
      int u = ug * 4 + ul;
      size_t cidx = (size_t)u * 2048 + m;
      float cold = (MODE == 1) ? c0w[cidx] : 0.0f;
      float cn, hn;
      cell1s(g16[ul * 4 + 0], g16[ul * 4 + 1], g16[ul * 4 + 2], g16[ul * 4 + 3], cold, &cn, &hn);
      c0w[cidx] = cn;
      unsigned short s0 = bf16_trunc(hn);
      float r1 = hn - bf16_tof(s0);
      unsigned short s1 = bf16_trunc(r1);
      unsigned short s2 = bf16_trunc(r1 - bf16_tof(s1));
      sp0[ul] = (short)s0; sp1[ul] = (short)s1; sp2[ul] = (short)s2;
    }
    *(short4*)&wp[fo]             = make_short4(sp0[0], sp0[1], sp0[2], sp0[3]);
    *(short4*)&wp[fo + SPOFF]     = make_short4(sp1[0], sp1[1], sp1[2], sp1[3]);
    *(short4*)&wp[fo + 2 * SPOFF] = make_short4(sp2[0], sp2[1], sp2[2], sp2[3]);
    __syncthreads();
  }

  // ================= L1 phase =================
  if (MODE >= 1) {
    {
      int col = lane & 15, rb2 = (lane >> 4) * 4;
#pragma unroll
      for (int i = 0; i < 4; i++) {
        int mt = wid * 4 + i;
#pragma unroll
        for (int j = 0; j < 4; j++)
          gbuf[(mt * 16 + rb2 + j) * GBS + col] = aL1[i][j];
      }
    }
    __syncthreads();
    int slot = (t - 1) & 15;
    unsigned short* rp = (unsigned short*)(wsm + OFF_RINGF) +
                         ((size_t)slot * 8 + rg) * PANEL_US;
    float* r2 = wsm + OFF_RING2 + (size_t)slot * HSLAB;
    float h4[4];
    short sp0[4], sp1[4], sp2[4];
#pragma unroll
    for (int ul = 0; ul < 4; ul++) {
      int gg = ul * 4;
      float gi = lbias[16 + gg + 0] + gbuf[mloc * GBS + gg + 0];
      float gf = lbias[16 + gg + 1] + gbuf[mloc * GBS + gg + 1];
      float gt = lbias[16 + gg + 2] + gbuf[mloc * GBS + gg + 2];
      float go = lbias[16 + gg + 3] + gbuf[mloc * GBS + gg + 3];
      int u = ug * 4 + ul;
      size_t cidx = (size_t)u * 2048 + m;
      float cold = (t >= 2) ? c1w[cidx] : 0.0f;
      float cn, hn;
      cell1s(gi, gf, gt, go, cold, &cn, &hn);
      c1w[cidx] = cn;
      h4[ul] = hn;
      unsigned short s0 = bf16_trunc(hn);
      float r1v = hn - bf16_tof(s0);
      unsigned short s1 = bf16_trunc(r1v);
      unsigned short s2 = bf16_trunc(r1v - bf16_tof(s1));
      sp0[ul] = (short)s0; sp1[ul] = (short)s1; sp2[ul] = (short)s2;
    }
    *(short4*)&rp[fo]             = make_short4(sp0[0], sp0[1], sp0[2], sp0[3]);
    *(short4*)&rp[fo + SPOFF]     = make_short4(sp1[0], sp1[1], sp1[2], sp1[3]);
    *(short4*)&rp[fo + 2 * SPOFF] = make_short4(sp2[0], sp2[1], sp2[2], sp2[3]);
    *(float4*)&r2[(size_t)m * 256 + ug * 4] = make_float4(h4[0], h4[1], h4[2], h4[3]);
  }
}

// Head: FC + MDN for 16 slots x 2048 rows; wave = 8 rows. (unchanged)
__launch_bounds__(512, 2)
__global__ void vfpg_head(const float* __restrict__ ws, const float* __restrict__ fcb,
                          float* __restrict__ out, int tbase,
                          uint32_t k1a, uint32_t k1b, uint32_t k2a, uint32_t k2b) {
  __shared__ __align__(16) float hsw[8][8][Hdim];   // 64 KB
  const int tid = threadIdx.x;
  const int lane = tid & 63, wid = tid >> 6;
  const int rb8 = blockIdx.x * 8 + wid;
  const int slot = rb8 >> 8;
  const int mbase = (rb8 & 255) * 8;

  const float* r2 = ws + OFF_RING2 + (size_t)slot * HSLAB + (size_t)mbase * 256;
  const float4* WFCP = (const float4*)(ws + OFF_WFCP);

#pragma unroll
  for (int rr = 0; rr < 8; rr++)
    *(float4*)&hsw[wid][rr][lane * 4] = *(const float4*)&r2[rr * 256 + lane * 4];
  __builtin_amdgcn_s_waitcnt(0);

  float yg[8], ys[8], ym[8];
#pragma unroll
  for (int rr = 0; rr < 8; rr++) {
    yg[rr] = fcb[lane]; ys[rr] = fcb[64 + lane]; ym[rr] = fcb[128 + lane];
  }
#pragma unroll 2
  for (int k4 = 0; k4 < 64; k4++) {
    float4 h4[8];
#pragma unroll
    for (int rr = 0; rr < 8; rr++) h4[rr] = *(const float4*)&hsw[wid][rr][k4 * 4];
#pragma unroll
    for (int j = 0; j < 4; j++) {
      float4 w = WFCP[(k4 * 4 + j) * 64 + lane];
#pragma unroll
      for (int rr = 0; rr < 8; rr++) {
        float hv = (&h4[rr].x)[j];
        yg[rr] = fmaf(hv, w.x, yg[rr]);
        ys[rr] = fmaf(hv, w.y, ys[rr]);
        ym[rr] = fmaf(hv, w.z, ym[rr]);
      }
    }
  }
  int tt = tbase + slot;
#pragma unroll 1
  for (int rr = 0; rr < 8; rr++) {
    uint32_t rid = (uint32_t)(mbase + rr) * Tdim + (uint32_t)tt;
    mdn_head(yg[rr], ys[rr], ym[rr], lane, rid, k1a, k1b, k2a, k2b, out);
  }
}

extern "C" void kernel_launch(void* const* d_in, const int* in_sizes, int n_in,
                              void* d_out, int out_size, void* d_ws, size_t ws_size,
                              hipStream_t stream) {
  const float* z    = (const float*)d_in[0];
  const float* Wih0 = (const float*)d_in[1];
  const float* Whh0 = (const float*)d_in[2];
  const float* bih0 = (const float*)d_in[3];
  const float* bhh0 = (const float*)d_in[4];
  const float* Wih1 = (const float*)d_in[5];
  const float* Whh1 = (const float*)d_in[6];
  const float* bih1 = (const float*)d_in[7];
  const float* bhh1 = (const float*)d_in[8];
  const float* fcW  = (const float*)d_in[9];
  const float* fcb  = (const float*)d_in[10];
  float* ws = (float*)d_ws;
  float* out = (float*)d_out;

  if (ws_size < (size_t)WS_TOT * sizeof(float)) return;

  vfpg_prep<<<dim3(512), dim3(256), 0, stream>>>(
      Wih0, Whh0, Wih1, Whh1, fcW, bih0, bhh0, bih1, bhh1, ws);

  uint32_t k1a, k1b, k2a, k2b;
  tf2x32(0u, 42u, 0u, 0u, &k1a, &k1b);
  tf2x32(0u, 42u, 0u, 1u, &k2a, &k2b);

  vfpg_step<0><<<dim3(512), dim3(256), 0, stream>>>(z, ws, ws, 0);
  for (int t = 1; t <= 63; t++) {
    vfpg_step<1><<<dim3(512), dim3(256), 0, stream>>>(z, ws, ws, t);
    if (t == 16 || t == 32 || t == 48) {
      vfpg_head<<<dim3(512), dim3(512), 0, stream>>>(ws, fcb, out, t - 16,
                                                     k1a, k1b, k2a, k2b);
    }
  }
  vfpg_step<2><<<dim3(512), dim3(256), 0, stream>>>(z, ws, ws, 64);
  vfpg_head<<<dim3(512), dim3(512), 0, stream>>>(ws, fcb, out, 48, k1a, k1b, k2a, k2b);
}

// Round 15
// 2068.711 us; speedup vs baseline: 3.8099x; 1.0059x over previous
//
#include <hip/hip_runtime.h>
#include <stdint.h>
#include <stddef.h>

// Problem dims
#define Mdim 2048
#define Tdim 64
#define INdim 16
#define Hdim 256
#define NCdim 64
#define NUG 64
#define HSLAB (256 * 2048)
#define RSLOTS 16

typedef __attribute__((ext_vector_type(8))) short s16x8;
typedef __attribute__((ext_vector_type(4))) float f32x4;

// Panel (per tbuf/slot, per rg): [sp3][mt16][kt8][512] bf16  -> 196608 ushorts
#define PANEL_US (3 * 16 * 8 * 512)
#define SPOFF 65536   // 16*8*512, split stride in ushorts
// BFRAG per ug: [cls3][kt8][sp3][512] bf16 -> 36864 ushorts
#define BFRAG_US (3 * 8 * 3 * 512)

// ws float offsets
#define OFF_BFRAG 0                                    // 64 * 36864 us = 1179648 fl
#define OFF_WZ    1179648                              // [64][16 k][16 g] fp32
#define OFF_BB    (OFF_WZ + 64 * 256)                  // [64][32]
#define OFF_WFCP  (OFF_BB + 64 * 32)                   // [256][64] float4
#define OFF_H0P   (OFF_WFCP + 256 * 64 * 4)            // [2 tbuf][8 rg] panels: 1572864 fl
#define OFF_C0    (OFF_H0P + 1572864)
#define OFF_C1    (OFF_C0 + HSLAB)
#define OFF_RINGF (OFF_C1 + HSLAB)                     // [16 slot][8 rg] panels: 12582912 fl
#define OFF_RING2 (OFF_RINGF + 12582912)               // fp32 [16][2048 m][256 u]
#define WS_TOT    (OFF_RING2 + RSLOTS * HSLAB)         // 24856576 fl = 99.4 MB

#define ROTL32(v, s) (((v) << (s)) | ((v) >> (32 - (s))))

__host__ __device__ inline void tf2x32(uint32_t k0, uint32_t k1, uint32_t x0, uint32_t x1,
                                       uint32_t* o0, uint32_t* o1) {
  uint32_t ks2 = k0 ^ k1 ^ 0x1BD11BDAu;
  x0 += k0; x1 += k1;
  x0 += x1; x1 = ROTL32(x1, 13); x1 ^= x0;
  x0 += x1; x1 = ROTL32(x1, 15); x1 ^= x0;
  x0 += x1; x1 = ROTL32(x1, 26); x1 ^= x0;
  x0 += x1; x1 = ROTL32(x1, 6);  x1 ^= x0;
  x0 += k1; x1 += ks2 + 1u;
  x0 += x1; x1 = ROTL32(x1, 17); x1 ^= x0;
  x0 += x1; x1 = ROTL32(x1, 29); x1 ^= x0;
  x0 += x1; x1 = ROTL32(x1, 16); x1 ^= x0;
  x0 += x1; x1 = ROTL32(x1, 24); x1 ^= x0;
  x0 += ks2; x1 += k0 + 2u;
  x0 += x1; x1 = ROTL32(x1, 13); x1 ^= x0;
  x0 += x1; x1 = ROTL32(x1, 15); x1 ^= x0;
  x0 += x1; x1 = ROTL32(x1, 26); x1 ^= x0;
  x0 += x1; x1 = ROTL32(x1, 6);  x1 ^= x0;
  x0 += k0; x1 += k1 + 3u;
  x0 += x1; x1 = ROTL32(x1, 17); x1 ^= x0;
  x0 += x1; x1 = ROTL32(x1, 29); x1 ^= x0;
  x0 += x1; x1 = ROTL32(x1, 16); x1 ^= x0;
  x0 += x1; x1 = ROTL32(x1, 24); x1 ^= x0;
  x0 += k1; x1 += ks2 + 4u;
  x0 += x1; x1 = ROTL32(x1, 13); x1 ^= x0;
  x0 += x1; x1 = ROTL32(x1, 15); x1 ^= x0;
  x0 += x1; x1 = ROTL32(x1, 26); x1 ^= x0;
  x0 += x1; x1 = ROTL32(x1, 6);  x1 ^= x0;
  x0 += ks2; x1 += k0 + 5u;
  *o0 = x0; *o1 = x1;
}

__device__ inline uint32_t random_bits32(uint32_t ka, uint32_t kb, uint32_t p) {
  uint32_t a, b;
  tf2x32(ka, kb, 0u, p, &a, &b);
  return a ^ b;
}

__device__ inline float bits_to_u01(uint32_t bits) {
  return __uint_as_float((bits >> 9) | 0x3f800000u) - 1.0f;
}

__device__ inline float sigm_fast(float x) { return 1.0f / (1.0f + __expf(-x)); }

__device__ inline float erfinv_f32(float x) {
  float w = -log1pf(-x * x);
  float p;
  if (w < 5.0f) {
    w -= 2.5f;
    p = 2.81022636e-08f;
    p = fmaf(p, w, 3.43273939e-07f);
    p = fmaf(p, w, -3.5233877e-06f);
    p = fmaf(p, w, -4.39150654e-06f);
    p = fmaf(p, w, 0.00021858087f);
    p = fmaf(p, w, -0.00125372503f);
    p = fmaf(p, w, -0.00417768164f);
    p = fmaf(p, w, 0.246640727f);
    p = fmaf(p, w, 1.50140941f);
  } else {
    w = sqrtf(w) - 3.0f;
    p = -0.000200214257f;
    p = fmaf(p, w, 0.000100950558f);
    p = fmaf(p, w, 0.00134934322f);
    p = fmaf(p, w, -0.00367342844f);
    p = fmaf(p, w, 0.00573950773f);
    p = fmaf(p, w, -0.0076224613f);
    p = fmaf(p, w, 0.00943887047f);
    p = fmaf(p, w, 1.00167406f);
    p = fmaf(p, w, 2.83297682f);
  }
  return p * x;
}

__device__ inline void mdn_head(float yg, float ysg, float ym, int lane, uint32_t rid,
                                uint32_t k1a, uint32_t k1b, uint32_t k2a, uint32_t k2b,
                                float* __restrict__ out) {
  uint32_t pp = rid * (uint32_t)NCdim + (uint32_t)lane;
  uint32_t bits = random_bits32(k1a, k1b, pp);
  float u01 = bits_to_u01(bits);
  const float tinyf = 1.17549435e-38f;
  float uu = fmaxf(tinyf, u01 + tinyf);
  float gum = -logf(-logf(uu));
  float val = gum + yg;
  int idx = lane;
#pragma unroll
  for (int s = 1; s < 64; s <<= 1) {
    float ov = __shfl_xor(val, s);
    int oi = __shfl_xor(idx, s);
    if (ov > val || (ov == val && oi < idx)) { val = ov; idx = oi; }
  }
  float mu_sel = __shfl(ym, idx);
  float s_sel = __shfl(ysg, idx);

  uint32_t ebits = random_bits32(k2a, k2b, rid);
  float ue = bits_to_u01(ebits);
  const float lo = __uint_as_float(0xBF7FFFFFu);
  float un2 = fmaxf(lo, ue * 2.0f + lo);
  float eps = 1.41421356f * erfinv_f32(un2);

  float x_pred = mu_sel + expf(s_sel) * eps;

  float mx = yg;
#pragma unroll
  for (int s = 1; s < 64; s <<= 1) mx = fmaxf(mx, __shfl_xor(mx, s));
  float se = expf(yg - mx);
#pragma unroll
  for (int s = 1; s < 64; s <<= 1) se += __shfl_xor(se, s);
  float d = x_pred - ym;
  float lk = -0.5f * d * d - 66.0f * ysg - 58.812066f;
  float ts = expf(yg - mx + lk);
#pragma unroll
  for (int s = 1; s < 64; s <<= 1) ts += __shfl_xor(ts, s);
  float prob = ts / se;

  if (lane == 0) {
    out[rid] = x_pred;
    out[(size_t)Mdim * Tdim + rid] = prob;
  }
}

__device__ __host__ inline unsigned short bf16_trunc(float x) {
  union { float f; uint32_t u; } c; c.f = x;
  return (unsigned short)(c.u >> 16);
}
__device__ __host__ inline float bf16_tof(unsigned short s) {
  union { float f; uint32_t u; } c; c.u = ((uint32_t)s) << 16;
  return c.f;
}

// Prep: pack B-frags (bf16x3, frag-linear), WZ, biases, FC table. (unchanged)
__global__ void vfpg_prep(const float* __restrict__ Wih0, const float* __restrict__ Whh0,
                          const float* __restrict__ Wih1, const float* __restrict__ Whh1,
                          const float* __restrict__ fcW, const float* __restrict__ bih0,
                          const float* __restrict__ bhh0, const float* __restrict__ bih1,
                          const float* __restrict__ bhh1, float* __restrict__ ws) {
  int i0 = blockIdx.x * blockDim.x + threadIdx.x;
  int n = blockDim.x * gridDim.x;
  unsigned short* BF = (unsigned short*)(ws + OFF_BFRAG);
  for (int i = i0; i < 64 * 3 * 8 * 512; i += n) {
    int ug = i / 12288, r = i % 12288;
    int cls = r / 4096, r2 = r % 4096;
    int kt = r2 >> 9, pos = r2 & 511;
    int l = pos >> 3, e = pos & 7;
    int n16 = l & 15, lg = l >> 4;
    int k = kt * 32 + lg * 8 + e;
    int ul = n16 >> 2, ty = n16 & 3;
    int gd = ty * 256 + ug * 4 + ul;
    const float* W = (cls == 0) ? Whh0 : ((cls == 1) ? Wih1 : Whh1);
    float w = W[gd * 256 + k];
    unsigned short s0 = bf16_trunc(w);
    float r1 = w - bf16_tof(s0);
    unsigned short s1 = bf16_trunc(r1);
    unsigned short s2 = bf16_trunc(r1 - bf16_tof(s1));
    size_t base = ((size_t)(ug * 3 + cls) * 8 + kt) * (3 * 512) + pos;
    BF[base] = s0;
    BF[base + 512] = s1;
    BF[base + 1024] = s2;
  }
  for (int i = i0; i < 64 * 256; i += n) {
    int ug = i >> 8, k = (i >> 4) & 15, g = i & 15;
    int gd = (g & 3) * 256 + ug * 4 + (g >> 2);
    ws[OFF_WZ + i] = Wih0[gd * INdim + k];
  }
  for (int i = i0; i < 64 * 32; i += n) {
    int ug = i >> 5, r = i & 31, g = r & 15;
    int gd = (g & 3) * 256 + ug * 4 + (g >> 2);
    ws[OFF_BB + i] = (r < 16) ? (bih0[gd] + bhh0[gd]) : (bih1[gd] + bhh1[gd]);
  }
  float4* wfcp = (float4*)(ws + OFF_WFCP);
  for (int o = i0; o < 256 * 64; o += n) {
    int k = o >> 6, c = o & 63;
    wfcp[o] = make_float4(fcW[c * Hdim + k], fcW[(64 + c) * Hdim + k],
                          fcW[(128 + c) * Hdim + k], 0.0f);
  }
}

__device__ inline void cell1s(float gi, float gf, float gg, float go, float cold,
                              float* cn, float* hn) {
  float si = sigm_fast(gi), sf = sigm_fast(gf);
  float tg = fmaf(2.0f, sigm_fast(2.0f * gg), -1.0f);
  float so = sigm_fast(go);
  float cc = fmaf(sf, cold, si * tg);
  *cn = cc;
  *hn = so * fmaf(2.0f, sigm_fast(2.0f * cc), -1.0f);
}

#define GBS2 33   // gbuf row stride (32 gates + 1 pad)

// Launch t: layer0 step t + layer1 step t-1. MODE 0: t=0; 1: 1..63; 2: t=64.
// Grid 256 = 8 rg x 32 ugc (2 ugs/block). 512 thr, 8 waves; wave = 2 mt x 2 ugs.
template <int MODE>
__launch_bounds__(512, 2)
__global__ void vfpg_step(const float* __restrict__ z, const float* __restrict__ ws,
                          float* __restrict__ wsm, int t) {
  __shared__ unsigned short lB01[2 * 2 * 8 * 2 * 512];  // 64 KB: [ugl][cls2][kt][sp2][512]
  __shared__ __align__(16) unsigned char uni[81920];    // 80 KB: B-s2/hh1 region, later gbuf
  __shared__ float lz[2 * 256];
  __shared__ float lbias[64];

  const int tid = threadIdx.x;
  const int rg = blockIdx.x & 7, ugc = blockIdx.x >> 3;
  const int mb = rg * 256;
  const int lane = tid & 63, wid = tid >> 6;
  float* gbuf = (float*)uni;

  // cooperative load: both ugs' full BFRAG into LDS (split layout)
  // per-ug vec8 count = 3 cls * 8 kt * 3 sp * 64 v = 4608  (FIXED decode: /4608, not >>12)
  {
    const unsigned short* BF = (const unsigned short*)(ws + OFF_BFRAG);
    const unsigned short* BG0 = BF + (size_t)(ugc * 2 + 0) * BFRAG_US;
    const unsigned short* BG1 = BF + (size_t)(ugc * 2 + 1) * BFRAG_US;
    for (int i = tid; i < 2 * 4608; i += 512) {
      int ugl = i / 4608;
      int r = i % 4608;
      int cls = r / 1536;        // 1536 = 8 kt * 3 sp * 64 v
      int r2 = r % 1536;
      int kt = r2 / 192;         // 192 = 3 sp * 64 v
      int sp = (r2 / 64) % 3;
      int v = r2 & 63;
      const unsigned short* src = (ugl ? BG1 : BG0) + ((size_t)(cls * 8 + kt) * 3 + sp) * 512 + v * 8;
      s16x8 val = *(const s16x8*)src;
      if (cls < 2 && sp < 2) {
        ((s16x8*)lB01)[((((ugl * 2 + cls) * 8 + kt) * 2 + sp)) * 64 + v] = val;
      } else {
        int str = (cls == 2) ? (2 + sp) : cls;
        ((s16x8*)uni)[(((ugl * 5 + str) * 8 + kt)) * 64 + v] = val;
      }
    }
    if (tid < 128) ((float4*)lz)[tid] = ((const float4*)(ws + OFF_WZ + (ugc * 2) * 256))[tid];
    if (tid < 64) lbias[tid] = ws[OFF_BB + (ugc * 2) * 32 + tid];
  }
  __syncthreads();

  f32x4 aL0[2][2], aL1[2][2];   // [mt-sub i][ugl]
#pragma unroll
  for (int i = 0; i < 2; i++)
#pragma unroll
    for (int u = 0; u < 2; u++) { aL0[i][u] = (f32x4)0.0f; aL1[i][u] = (f32x4)0.0f; }

  if (MODE >= 1) {
    const unsigned short* p0 = (const unsigned short*)(ws + OFF_H0P) +
                               ((size_t)((t - 1) & 1) * 8 + rg) * PANEL_US;
    const unsigned short* p1 = (const unsigned short*)(ws + OFF_RINGF) +
                               ((size_t)((t - 2) & 15) * 8 + rg) * PANEL_US;
    const bool doH1 = (t >= 2);
    const s16x8* pL = (const s16x8*)lB01;
    const s16x8* pU = (const s16x8*)uni;

    s16x8 Ab0[6], Ab1[6];
    {
      size_t fb = ((size_t)(wid * 2) * 8 + 0) * 512 + lane * 8;
      Ab0[0] = *(const s16x8*)(p0 + fb);
      Ab0[1] = *(const s16x8*)(p0 + fb + SPOFF);
      Ab0[2] = *(const s16x8*)(p0 + fb + 2 * SPOFF);
      if (doH1) {
        Ab0[3] = *(const s16x8*)(p1 + fb);
        Ab0[4] = *(const s16x8*)(p1 + fb + SPOFF);
        Ab0[5] = *(const s16x8*)(p1 + fb + 2 * SPOFF);
      }
    }

#pragma unroll 1
    for (int kt = 0; kt < 8; kt++) {
      // hoist B frags for this kt (both ugs) from LDS
      s16x8 bL0s0[2], bL0s1[2], bL0s2[2], bIs0[2], bIs1[2], bIs2[2], bHs0[2], bHs1[2], bHs2[2];
#pragma unroll
      for (int u = 0; u < 2; u++) {
        if (MODE == 1) {
          bL0s0[u] = pL[(((u * 2 + 0) * 8 + kt) * 2 + 0) * 64 + lane];
          bL0s1[u] = pL[(((u * 2 + 0) * 8 + kt) * 2 + 1) * 64 + lane];
          bL0s2[u] = pU[((u * 5 + 0) * 8 + kt) * 64 + lane];
        }
        bIs0[u] = pL[(((u * 2 + 1) * 8 + kt) * 2 + 0) * 64 + lane];
        bIs1[u] = pL[(((u * 2 + 1) * 8 + kt) * 2 + 1) * 64 + lane];
        bIs2[u] = pU[((u * 5 + 1) * 8 + kt) * 64 + lane];
        if (doH1) {
          bHs0[u] = pU[((u * 5 + 2) * 8 + kt) * 64 + lane];
          bHs1[u] = pU[((u * 5 + 3) * 8 + kt) * 64 + lane];
          bHs2[u] = pU[((u * 5 + 4) * 8 + kt) * 64 + lane];
        }
      }
#pragma unroll
      for (int i = 0; i < 2; i++) {
        s16x8* cur = (i & 1) ? Ab1 : Ab0;
        s16x8* nxt = (i & 1) ? Ab0 : Ab1;
        int nkt = (i < 1) ? kt : kt + 1;
        int ni = (i < 1) ? 1 : 0;
        if (nkt < 8) {
          size_t fb = ((size_t)(wid * 2 + ni) * 8 + nkt) * 512 + lane * 8;
          nxt[0] = *(const s16x8*)(p0 + fb);
          nxt[1] = *(const s16x8*)(p0 + fb + SPOFF);
          nxt[2] = *(const s16x8*)(p0 + fb + 2 * SPOFF);
          if (doH1) {
            nxt[3] = *(const s16x8*)(p1 + fb);
            nxt[4] = *(const s16x8*)(p1 + fb + SPOFF);
            nxt[5] = *(const s16x8*)(p1 + fb + 2 * SPOFF);
          }
        }
        s16x8 a0 = cur[0], a1 = cur[1], a2 = cur[2];
#pragma unroll
        for (int u = 0; u < 2; u++) {
          if (MODE == 1) {
            aL0[i][u] = __builtin_amdgcn_mfma_f32_16x16x32_bf16(a0, bL0s0[u], aL0[i][u], 0, 0, 0);
            aL0[i][u] = __builtin_amdgcn_mfma_f32_16x16x32_bf16(a0, bL0s1[u], aL0[i][u], 0, 0, 0);
            aL0[i][u] = __builtin_amdgcn_mfma_f32_16x16x32_bf16(a1, bL0s0[u], aL0[i][u], 0, 0, 0);
            aL0[i][u] = __builtin_amdgcn_mfma_f32_16x16x32_bf16(a1, bL0s1[u], aL0[i][u], 0, 0, 0);
            aL0[i][u] = __builtin_amdgcn_mfma_f32_16x16x32_bf16(a0, bL0s2[u], aL0[i][u], 0, 0, 0);
            aL0[i][u] = __builtin_amdgcn_mfma_f32_16x16x32_bf16(a2, bL0s0[u], aL0[i][u], 0, 0, 0);
          }
          aL1[i][u] = __builtin_amdgcn_mfma_f32_16x16x32_bf16(a0, bIs0[u], aL1[i][u], 0, 0, 0);
          aL1[i][u] = __builtin_amdgcn_mfma_f32_16x16x32_bf16(a0, bIs1[u], aL1[i][u], 0, 0, 0);
          aL1[i][u] = __builtin_amdgcn_mfma_f32_16x16x32_bf16(a1, bIs0[u], aL1[i][u], 0, 0, 0);
          aL1[i][u] = __builtin_amdgcn_mfma_f32_16x16x32_bf16(a1, bIs1[u], aL1[i][u], 0, 0, 0);
          aL1[i][u] = __builtin_amdgcn_mfma_f32_16x16x32_bf16(a0, bIs2[u], aL1[i][u], 0, 0, 0);
          aL1[i][u] = __builtin_amdgcn_mfma_f32_16x16x32_bf16(a2, bIs0[u], aL1[i][u], 0, 0, 0);
          if (doH1) {
            s16x8 c0 = cur[3], c1 = cur[4], c2 = cur[5];
            aL1[i][u] = __builtin_amdgcn_mfma_f32_16x16x32_bf16(c0, bHs0[u], aL1[i][u], 0, 0, 0);
            aL1[i][u] = __builtin_amdgcn_mfma_f32_16x16x32_bf16(c0, bHs1[u], aL1[i][u], 0, 0, 0);
            aL1[i][u] = __builtin_amdgcn_mfma_f32_16x16x32_bf16(c1, bHs0[u], aL1[i][u], 0, 0, 0);
            aL1[i][u] = __builtin_amdgcn_mfma_f32_16x16x32_bf16(c1, bHs1[u], aL1[i][u], 0, 0, 0);
            aL1[i][u] = __builtin_amdgcn_mfma_f32_16x16x32_bf16(c0, bHs2[u], aL1[i][u], 0, 0, 0);
            aL1[i][u] = __builtin_amdgcn_mfma_f32_16x16x32_bf16(c2, bHs0[u], aL1[i][u], 0, 0, 0);
          }
        }
      }
    }
  }
  __syncthreads();   // uni region: B-s2 reads done; becomes gbuf

  float* c0w = wsm + OFF_C0;
  float* c1w = wsm + OFF_C1;
  const int ugl = tid >> 8;
  const int mloc = tid & 255;
  const int m = mb + mloc;
  const int ug = ugc * 2 + ugl;
  const int mtc = mloc >> 4, mrowc = mloc & 15;
  const int ktw = ug >> 3;
  const int lgw = (ug & 7) >> 1;
  const int ebase = (ug * 4) & 7;
  const int lww = lgw * 16 + mrowc;
  const size_t fo = ((size_t)mtc * 8 + ktw) * 512 + lww * 8 + ebase;

  // ================= L0 phase =================
  if (MODE <= 1) {
    if (MODE == 1) {
      int col = lane & 15, rb2 = (lane >> 4) * 4;
#pragma unroll
      for (int i = 0; i < 2; i++)
#pragma unroll
        for (int u = 0; u < 2; u++)
#pragma unroll
          for (int j = 0; j < 4; j++)
            gbuf[((wid * 2 + i) * 16 + rb2 + j) * GBS2 + u * 16 + col] = aL0[i][u][j];
    }
    __syncthreads();
    float zr[16];
#pragma unroll
    for (int f4 = 0; f4 < 4; f4++)
      *(float4*)&zr[f4 * 4] = *(const float4*)&z[(size_t)m * 1024 + t * 16 + f4 * 4];
    float g16[16];
#pragma unroll
    for (int gg = 0; gg < 16; gg++)
      g16[gg] = lbias[ugl * 32 + gg] + ((MODE == 1) ? gbuf[mloc * GBS2 + ugl * 16 + gg] : 0.0f);
    const float* lzu = lz + ugl * 256;
#pragma unroll
    for (int f = 0; f < 16; f++) {
      float zv = zr[f];
      float4 w0 = *(const float4*)&lzu[f * 16 + 0];
      float4 w1 = *(const float4*)&lzu[f * 16 + 4];
      float4 w2 = *(const float4*)&lzu[f * 16 + 8];
      float4 w3 = *(const float4*)&lzu[f * 16 + 12];
      g16[0] = fmaf(zv, w0.x, g16[0]);  g16[1] = fmaf(zv, w0.y, g16[1]);
      g16[2] = fmaf(zv, w0.z, g16[2]);  g16[3] = fmaf(zv, w0.w, g16[3]);
      g16[4] = fmaf(zv, w1.x, g16[4]);  g16[5] = fmaf(zv, w1.y, g16[5]);
      g16[6] = fmaf(zv, w1.z, g16[6]);  g16[7] = fmaf(zv, w1.w, g16[7]);
      g16[8] = fmaf(zv, w2.x, g16[8]);  g16[9] = fmaf(zv, w2.y, g16[9]);
      g16[10] = fmaf(zv, w2.z, g16[10]); g16[11] = fmaf(zv, w2.w, g16[11]);
      g16[12] = fmaf(zv, w3.x, g16[12]); g16[13] = fmaf(zv, w3.y, g16[13]);
      g16[14] = fmaf(zv, w3.z, g16[14]); g16[15] = fmaf(zv, w3.w, g16[15]);
    }
    unsigned short* wp = (unsigned short*)(wsm + OFF_H0P) +
                         ((size_t)(t & 1) * 8 + rg) * PANEL_US;
    short sp0[4], sp1[4], sp2[4];
#pragma unroll
    for (int ul = 0; ul < 4; ul++) {
      int u = ug * 4 + ul;
      size_t cidx = (size_t)u * 2048 + m;
      float cold = (MODE == 1) ? c0w[cidx] : 0.0f;
      float cn, hn;
      cell1s(g16[ul * 4 + 0], g16[ul * 4 + 1], g16[ul * 4 + 2], g16[ul * 4 + 3], cold, &cn, &hn);
      c0w[cidx] = cn;
      unsigned short s0 = bf16_trunc(hn);
      float r1 = hn - bf16_tof(s0);
      unsigned short s1 = bf16_trunc(r1);
      unsigned short s2 = bf16_trunc(r1 - bf16_tof(s1));
      sp0[ul] = (short)s0; sp1[ul] = (short)s1; sp2[ul] = (short)s2;
    }
    *(short4*)&wp[fo]             = make_short4(sp0[0], sp0[1], sp0[2], sp0[3]);
    *(short4*)&wp[fo + SPOFF]     = make_short4(sp1[0], sp1[1], sp1[2], sp1[3]);
    *(short4*)&wp[fo + 2 * SPOFF] = make_short4(sp2[0], sp2[1], sp2[2], sp2[3]);
    __syncthreads();
  }

  // ================= L1 phase =================
  if (MODE >= 1) {
    {
      int col = lane & 15, rb2 = (lane >> 4) * 4;
#pragma unroll
      for (int i = 0; i < 2; i++)
#pragma unroll
        for (int u = 0; u < 2; u++)
#pragma unroll
          for (int j = 0; j < 4; j++)
            gbuf[((wid * 2 + i) * 16 + rb2 + j) * GBS2 + u * 16 + col] = aL1[i][u][j];
    }
    __syncthreads();
    int slot = (t - 1) & 15;
    unsigned short* rp = (unsigned short*)(wsm + OFF_RINGF) +
                         ((size_t)slot * 8 + rg) * PANEL_US;
    float* r2 = wsm + OFF_RING2 + (size_t)slot * HSLAB;
    float h4[4];
    short sp0[4], sp1[4], sp2[4];
#pragma unroll
    for (int ul = 0; ul < 4; ul++) {
      float gi = lbias[ugl * 32 + 16 + ul * 4 + 0] + gbuf[mloc * GBS2 + ugl * 16 + ul * 4 + 0];
      float gf = lbias[ugl * 32 + 16 + ul * 4 + 1] + gbuf[mloc * GBS2 + ugl * 16 + ul * 4 + 1];
      float gt = lbias[ugl * 32 + 16 + ul * 4 + 2] + gbuf[mloc * GBS2 + ugl * 16 + ul * 4 + 2];
      float go = lbias[ugl * 32 + 16 + ul * 4 + 3] + gbuf[mloc * GBS2 + ugl * 16 + ul * 4 + 3];
      int u = ug * 4 + ul;
      size_t cidx = (size_t)u * 2048 + m;
      float cold = (t >= 2) ? c1w[cidx] : 0.0f;
      float cn, hn;
      cell1s(gi, gf, gt, go, cold, &cn, &hn);
      c1w[cidx] = cn;
      h4[ul] = hn;
      unsigned short s0 = bf16_trunc(hn);
      float r1v = hn - bf16_tof(s0);
      unsigned short s1 = bf16_trunc(r1v);
      unsigned short s2 = bf16_trunc(r1v - bf16_tof(s1));
      sp0[ul] = (short)s0; sp1[ul] = (short)s1; sp2[ul] = (short)s2;
    }
    *(short4*)&rp[fo]             = make_short4(sp0[0], sp0[1], sp0[2], sp0[3]);
    *(short4*)&rp[fo + SPOFF]     = make_short4(sp1[0], sp1[1], sp1[2], sp1[3]);
    *(short4*)&rp[fo + 2 * SPOFF] = make_short4(sp2[0], sp2[1], sp2[2], sp2[3]);
    *(float4*)&r2[(size_t)m * 256 + ug * 4] = make_float4(h4[0], h4[1], h4[2], h4[3]);
  }
}

// Head: FC + MDN for 16 slots x 2048 rows; wave = 8 rows. (unchanged)
__launch_bounds__(512, 2)
__global__ void vfpg_head(const float* __restrict__ ws, const float* __restrict__ fcb,
                          float* __restrict__ out, int tbase,
                          uint32_t k1a, uint32_t k1b, uint32_t k2a, uint32_t k2b) {
  __shared__ __align__(16) float hsw[8][8][Hdim];   // 64 KB
  const int tid = threadIdx.x;
  const int lane = tid & 63, wid = tid >> 6;
  const int rb8 = blockIdx.x * 8 + wid;
  const int slot = rb8 >> 8;
  const int mbase = (rb8 & 255) * 8;

  const float* r2 = ws + OFF_RING2 + (size_t)slot * HSLAB + (size_t)mbase * 256;
  const float4* WFCP = (const float4*)(ws + OFF_WFCP);

#pragma unroll
  for (int rr = 0; rr < 8; rr++)
    *(float4*)&hsw[wid][rr][lane * 4] = *(const float4*)&r2[rr * 256 + lane * 4];
  __builtin_amdgcn_s_waitcnt(0);

  float yg[8], ys[8], ym[8];
#pragma unroll
  for (int rr = 0; rr < 8; rr++) {
    yg[rr] = fcb[lane]; ys[rr] = fcb[64 + lane]; ym[rr] = fcb[128 + lane];
  }
#pragma unroll 2
  for (int k4 = 0; k4 < 64; k4++) {
    float4 h4[8];
#pragma unroll
    for (int rr = 0; rr < 8; rr++) h4[rr] = *(const float4*)&hsw[wid][rr][k4 * 4];
#pragma unroll
    for (int j = 0; j < 4; j++) {
      float4 w = WFCP[(k4 * 4 + j) * 64 + lane];
#pragma unroll
      for (int rr = 0; rr < 8; rr++) {
        float hv = (&h4[rr].x)[j];
        yg[rr] = fmaf(hv, w.x, yg[rr]);
        ys[rr] = fmaf(hv, w.y, ys[rr]);
        ym[rr] = fmaf(hv, w.z, ym[rr]);
      }
    }
  }
  int tt = tbase + slot;
#pragma unroll 1
  for (int rr = 0; rr < 8; rr++) {
    uint32_t rid = (uint32_t)(mbase + rr) * Tdim + (uint32_t)tt;
    mdn_head(yg[rr], ys[rr], ym[rr], lane, rid, k1a, k1b, k2a, k2b, out);
  }
}

extern "C" void kernel_launch(void* const* d_in, const int* in_sizes, int n_in,
                              void* d_out, int out_size, void* d_ws, size_t ws_size,
                              hipStream_t stream) {
  const float* z    = (const float*)d_in[0];
  const float* Wih0 = (const float*)d_in[1];
  const float* Whh0 = (const float*)d_in[2];
  const float* bih0 = (const float*)d_in[3];
  const float* bhh0 = (const float*)d_in[4];
  const float* Wih1 = (const float*)d_in[5];
  const float* Whh1 = (const float*)d_in[6];
  const float* bih1 = (const float*)d_in[7];
  const float* bhh1 = (const float*)d_in[8];
  const float* fcW  = (const float*)d_in[9];
  const float* fcb  = (const float*)d_in[10];
  float* ws = (float*)d_ws;
  float* out = (float*)d_out;

  if (ws_size < (size_t)WS_TOT * sizeof(float)) return;

  vfpg_prep<<<dim3(512), dim3(256), 0, stream>>>(
      Wih0, Whh0, Wih1, Whh1, fcW, bih0, bhh0, bih1, bhh1, ws);

  uint32_t k1a, k1b, k2a, k2b;
  tf2x32(0u, 42u, 0u, 0u, &k1a, &k1b);
  tf2x32(0u, 42u, 0u, 1u, &k2a, &k2b);

  vfpg_step<0><<<dim3(256), dim3(512), 0, stream>>>(z, ws, ws, 0);
  for (int t = 1; t <= 63; t++) {
    vfpg_step<1><<<dim3(256), dim3(512), 0, stream>>>(z, ws, ws, t);
    if (t == 16 || t == 32 || t == 48) {
      vfpg_head<<<dim3(512), dim3(512), 0, stream>>>(ws, fcb, out, t - 16,
                                                     k1a, k1b, k2a, k2b);
    }
  }
  vfpg_step<2><<<dim3(256), dim3(512), 0, stream>>>(z, ws, ws, 64);
  vfpg_head<<<dim3(512), dim3(512), 0, stream>>>(ws, fcb, out, 48, k1a, k1b, k2a, k2b);
}

// Round 16
// 1931.993 us; speedup vs baseline: 4.0795x; 1.0708x over previous
//
#include <hip/hip_runtime.h>
#include <stdint.h>
#include <stddef.h>

// Problem dims
#define Mdim 2048
#define Tdim 64
#define INdim 16
#define Hdim 256
#define NCdim 64
#define NUG 64
#define HSLAB (256 * 2048)
#define RSLOTS 16

typedef __attribute__((ext_vector_type(8))) short s16x8;
typedef __attribute__((ext_vector_type(4))) float f32x4;

// Panel (per tbuf/slot, per rg): [sp3][mt16][kt8][512] bf16  -> 196608 ushorts
#define PANEL_US (3 * 16 * 8 * 512)
#define SPOFF 65536   // 16*8*512, split stride in ushorts
// BFRAG per ug: [cls3][kt8][sp3][512] bf16 -> 36864 ushorts
#define BFRAG_US (3 * 8 * 3 * 512)

// ws float offsets
#define OFF_BFRAG 0                                    // 64 * 36864 us = 1179648 fl
#define OFF_WZ    1179648                              // [64][16 k][16 g] fp32
#define OFF_BB    (OFF_WZ + 64 * 256)                  // [64][32]
#define OFF_WFCP  (OFF_BB + 64 * 32)                   // (unused, reserved)
#define OFF_H0P   (OFF_WFCP + 256 * 64 * 4)            // [2 tbuf][8 rg] panels
#define OFF_C0    (OFF_H0P + 1572864)
#define OFF_C1    (OFF_C0 + HSLAB)
#define OFF_RINGF (OFF_C1 + HSLAB)                     // [16 slot][8 rg] panels
#define OFF_Y     (OFF_RINGF + 12582912)               // y[16 slot][2048 m][192] fp32 (6.29M fl)
#define OFF_FCB3  (OFF_Y + RSLOTS * HSLAB)             // FC B-frags bf16x3: 73728 fl
#define WS_TOT    (OFF_FCB3 + 73728)                   // 24930304 fl = 99.7 MB

#define ROTL32(v, s) (((v) << (s)) | ((v) >> (32 - (s))))

__host__ __device__ inline void tf2x32(uint32_t k0, uint32_t k1, uint32_t x0, uint32_t x1,
                                       uint32_t* o0, uint32_t* o1) {
  uint32_t ks2 = k0 ^ k1 ^ 0x1BD11BDAu;
  x0 += k0; x1 += k1;
  x0 += x1; x1 = ROTL32(x1, 13); x1 ^= x0;
  x0 += x1; x1 = ROTL32(x1, 15); x1 ^= x0;
  x0 += x1; x1 = ROTL32(x1, 26); x1 ^= x0;
  x0 += x1; x1 = ROTL32(x1, 6);  x1 ^= x0;
  x0 += k1; x1 += ks2 + 1u;
  x0 += x1; x1 = ROTL32(x1, 17); x1 ^= x0;
  x0 += x1; x1 = ROTL32(x1, 29); x1 ^= x0;
  x0 += x1; x1 = ROTL32(x1, 16); x1 ^= x0;
  x0 += x1; x1 = ROTL32(x1, 24); x1 ^= x0;
  x0 += ks2; x1 += k0 + 2u;
  x0 += x1; x1 = ROTL32(x1, 13); x1 ^= x0;
  x0 += x1; x1 = ROTL32(x1, 15); x1 ^= x0;
  x0 += x1; x1 = ROTL32(x1, 26); x1 ^= x0;
  x0 += x1; x1 = ROTL32(x1, 6);  x1 ^= x0;
  x0 += k0; x1 += k1 + 3u;
  x0 += x1; x1 = ROTL32(x1, 17); x1 ^= x0;
  x0 += x1; x1 = ROTL32(x1, 29); x1 ^= x0;
  x0 += x1; x1 = ROTL32(x1, 16); x1 ^= x0;
  x0 += x1; x1 = ROTL32(x1, 24); x1 ^= x0;
  x0 += k1; x1 += ks2 + 4u;
  x0 += x1; x1 = ROTL32(x1, 13); x1 ^= x0;
  x0 += x1; x1 = ROTL32(x1, 15); x1 ^= x0;
  x0 += x1; x1 = ROTL32(x1, 26); x1 ^= x0;
  x0 += x1; x1 = ROTL32(x1, 6);  x1 ^= x0;
  x0 += ks2; x1 += k0 + 5u;
  *o0 = x0; *o1 = x1;
}

__device__ inline uint32_t random_bits32(uint32_t ka, uint32_t kb, uint32_t p) {
  uint32_t a, b;
  tf2x32(ka, kb, 0u, p, &a, &b);
  return a ^ b;
}

__device__ inline float bits_to_u01(uint32_t bits) {
  return __uint_as_float((bits >> 9) | 0x3f800000u) - 1.0f;
}

__device__ inline float sigm_fast(float x) { return 1.0f / (1.0f + __expf(-x)); }

__device__ inline float erfinv_f32(float x) {
  float w = -log1pf(-x * x);
  float p;
  if (w < 5.0f) {
    w -= 2.5f;
    p = 2.81022636e-08f;
    p = fmaf(p, w, 3.43273939e-07f);
    p = fmaf(p, w, -3.5233877e-06f);
    p = fmaf(p, w, -4.39150654e-06f);
    p = fmaf(p, w, 0.00021858087f);
    p = fmaf(p, w, -0.00125372503f);
    p = fmaf(p, w, -0.00417768164f);
    p = fmaf(p, w, 0.246640727f);
    p = fmaf(p, w, 1.50140941f);
  } else {
    w = sqrtf(w) - 3.0f;
    p = -0.000200214257f;
    p = fmaf(p, w, 0.000100950558f);
    p = fmaf(p, w, 0.00134934322f);
    p = fmaf(p, w, -0.00367342844f);
    p = fmaf(p, w, 0.00573950773f);
    p = fmaf(p, w, -0.0076224613f);
    p = fmaf(p, w, 0.00943887047f);
    p = fmaf(p, w, 1.00167406f);
    p = fmaf(p, w, 2.83297682f);
  }
  return p * x;
}

__device__ inline void mdn_head(float yg, float ysg, float ym, int lane, uint32_t rid,
                                uint32_t k1a, uint32_t k1b, uint32_t k2a, uint32_t k2b,
                                float* __restrict__ out) {
  uint32_t pp = rid * (uint32_t)NCdim + (uint32_t)lane;
  uint32_t bits = random_bits32(k1a, k1b, pp);
  float u01 = bits_to_u01(bits);
  const float tinyf = 1.17549435e-38f;
  float uu = fmaxf(tinyf, u01 + tinyf);
  float gum = -logf(-logf(uu));
  float val = gum + yg;
  int idx = lane;
#pragma unroll
  for (int s = 1; s < 64; s <<= 1) {
    float ov = __shfl_xor(val, s);
    int oi = __shfl_xor(idx, s);
    if (ov > val || (ov == val && oi < idx)) { val = ov; idx = oi; }
  }
  float mu_sel = __shfl(ym, idx);
  float s_sel = __shfl(ysg, idx);

  uint32_t ebits = random_bits32(k2a, k2b, rid);
  float ue = bits_to_u01(ebits);
  const float lo = __uint_as_float(0xBF7FFFFFu);
  float un2 = fmaxf(lo, ue * 2.0f + lo);
  float eps = 1.41421356f * erfinv_f32(un2);

  float x_pred = mu_sel + expf(s_sel) * eps;

  float mx = yg;
#pragma unroll
  for (int s = 1; s < 64; s <<= 1) mx = fmaxf(mx, __shfl_xor(mx, s));
  float se = expf(yg - mx);
#pragma unroll
  for (int s = 1; s < 64; s <<= 1) se += __shfl_xor(se, s);
  float d = x_pred - ym;
  float lk = -0.5f * d * d - 66.0f * ysg - 58.812066f;
  float ts = expf(yg - mx + lk);
#pragma unroll
  for (int s = 1; s < 64; s <<= 1) ts += __shfl_xor(ts, s);
  float prob = ts / se;

  if (lane == 0) {
    out[rid] = x_pred;
    out[(size_t)Mdim * Tdim + rid] = prob;
  }
}

__device__ __host__ inline unsigned short bf16_trunc(float x) {
  union { float f; uint32_t u; } c; c.f = x;
  return (unsigned short)(c.u >> 16);
}
__device__ __host__ inline float bf16_tof(unsigned short s) {
  union { float f; uint32_t u; } c; c.u = ((uint32_t)s) << 16;
  return c.f;
}

// Prep: pack LSTM B-frags (bf16x3), WZ, biases, FC B-frags (bf16x3).
__global__ void vfpg_prep(const float* __restrict__ Wih0, const float* __restrict__ Whh0,
                          const float* __restrict__ Wih1, const float* __restrict__ Whh1,
                          const float* __restrict__ fcW, const float* __restrict__ bih0,
                          const float* __restrict__ bhh0, const float* __restrict__ bih1,
                          const float* __restrict__ bhh1, float* __restrict__ ws) {
  int i0 = blockIdx.x * blockDim.x + threadIdx.x;
  int n = blockDim.x * gridDim.x;
  unsigned short* BF = (unsigned short*)(ws + OFF_BFRAG);
  for (int i = i0; i < 64 * 3 * 8 * 512; i += n) {
    int ug = i / 12288, r = i % 12288;
    int cls = r / 4096, r2 = r % 4096;
    int kt = r2 >> 9, pos = r2 & 511;
    int l = pos >> 3, e = pos & 7;
    int n16 = l & 15, lg = l >> 4;
    int k = kt * 32 + lg * 8 + e;
    int ul = n16 >> 2, ty = n16 & 3;
    int gd = ty * 256 + ug * 4 + ul;
    const float* W = (cls == 0) ? Whh0 : ((cls == 1) ? Wih1 : Whh1);
    float w = W[gd * 256 + k];
    unsigned short s0 = bf16_trunc(w);
    float r1 = w - bf16_tof(s0);
    unsigned short s1 = bf16_trunc(r1);
    unsigned short s2 = bf16_trunc(r1 - bf16_tof(s1));
    size_t base = ((size_t)(ug * 3 + cls) * 8 + kt) * (3 * 512) + pos;
    BF[base] = s0;
    BF[base + 512] = s1;
    BF[base + 1024] = s2;
  }
  for (int i = i0; i < 64 * 256; i += n) {
    int ug = i >> 8, k = (i >> 4) & 15, g = i & 15;
    int gd = (g & 3) * 256 + ug * 4 + (g >> 2);
    ws[OFF_WZ + i] = Wih0[gd * INdim + k];
  }
  for (int i = i0; i < 64 * 32; i += n) {
    int ug = i >> 5, r = i & 31, g = r & 15;
    int gd = (g & 3) * 256 + ug * 4 + (g >> 2);
    ws[OFF_BB + i] = (r < 16) ? (bih0[gd] + bhh0[gd]) : (bih1[gd] + bhh1[gd]);
  }
  // FC B-frags: [nt12][kt8][sp3*512]; c = nt*16 + (l&15); k = kt*32 + (l>>4)*8 + e
  unsigned short* BFC = (unsigned short*)(ws + OFF_FCB3);
  for (int i = i0; i < 12 * 8 * 512; i += n) {
    int ntkt = i >> 9, pos = i & 511;
    int nt = ntkt >> 3, kt = ntkt & 7;
    int l = pos >> 3, e = pos & 7;
    int c = nt * 16 + (l & 15);
    int k = kt * 32 + (l >> 4) * 8 + e;
    float w = fcW[c * Hdim + k];
    unsigned short s0 = bf16_trunc(w);
    float r1 = w - bf16_tof(s0);
    unsigned short s1 = bf16_trunc(r1);
    unsigned short s2 = bf16_trunc(r1 - bf16_tof(s1));
    size_t base = (size_t)ntkt * (3 * 512) + pos;
    BFC[base] = s0;
    BFC[base + 512] = s1;
    BFC[base + 1024] = s2;
  }
}

__device__ inline void cell1s(float gi, float gf, float gg, float go, float cold,
                              float* cn, float* hn) {
  float si = sigm_fast(gi), sf = sigm_fast(gf);
  float tg = fmaf(2.0f, sigm_fast(2.0f * gg), -1.0f);
  float so = sigm_fast(go);
  float cc = fmaf(sf, cold, si * tg);
  *cn = cc;
  *hn = so * fmaf(2.0f, sigm_fast(2.0f * cc), -1.0f);
}

#define GBS2 33   // gbuf row stride (32 gates + 1 pad)

// Launch t: layer0 step t + layer1 step t-1. MODE 0: t=0; 1: 1..63; 2: t=64.
// Grid 256 = 8 rg x 32 ugc (2 ugs/block). 512 thr, 8 waves; wave = 2 mt x 2 ugs.
template <int MODE>
__launch_bounds__(512, 2)
__global__ void vfpg_step(const float* __restrict__ z, const float* __restrict__ ws,
                          float* __restrict__ wsm, int t) {
  __shared__ unsigned short lB01[2 * 2 * 8 * 2 * 512];  // 64 KB
  __shared__ __align__(16) unsigned char uni[81920];    // 80 KB
  __shared__ float lz[2 * 256];
  __shared__ float lbias[64];

  const int tid = threadIdx.x;
  const int rg = blockIdx.x & 7, ugc = blockIdx.x >> 3;
  const int mb = rg * 256;
  const int lane = tid & 63, wid = tid >> 6;
  float* gbuf = (float*)uni;

  {
    const unsigned short* BF = (const unsigned short*)(ws + OFF_BFRAG);
    const unsigned short* BG0 = BF + (size_t)(ugc * 2 + 0) * BFRAG_US;
    const unsigned short* BG1 = BF + (size_t)(ugc * 2 + 1) * BFRAG_US;
    for (int i = tid; i < 2 * 4608; i += 512) {
      int ugl = i / 4608;
      int r = i % 4608;
      int cls = r / 1536;
      int r2 = r % 1536;
      int kt = r2 / 192;
      int sp = (r2 / 64) % 3;
      int v = r2 & 63;
      const unsigned short* src = (ugl ? BG1 : BG0) + ((size_t)(cls * 8 + kt) * 3 + sp) * 512 + v * 8;
      s16x8 val = *(const s16x8*)src;
      if (cls < 2 && sp < 2) {
        ((s16x8*)lB01)[((((ugl * 2 + cls) * 8 + kt) * 2 + sp)) * 64 + v] = val;
      } else {
        int str = (cls == 2) ? (2 + sp) : cls;
        ((s16x8*)uni)[(((ugl * 5 + str) * 8 + kt)) * 64 + v] = val;
      }
    }
    if (tid < 128) ((float4*)lz)[tid] = ((const float4*)(ws + OFF_WZ + (ugc * 2) * 256))[tid];
    if (tid < 64) lbias[tid] = ws[OFF_BB + (ugc * 2) * 32 + tid];
  }
  __syncthreads();

  f32x4 aL0[2][2], aL1[2][2];
#pragma unroll
  for (int i = 0; i < 2; i++)
#pragma unroll
    for (int u = 0; u < 2; u++) { aL0[i][u] = (f32x4)0.0f; aL1[i][u] = (f32x4)0.0f; }

  if (MODE >= 1) {
    const unsigned short* p0 = (const unsigned short*)(ws + OFF_H0P) +
                               ((size_t)((t - 1) & 1) * 8 + rg) * PANEL_US;
    const unsigned short* p1 = (const unsigned short*)(ws + OFF_RINGF) +
                               ((size_t)((t - 2) & 15) * 8 + rg) * PANEL_US;
    const bool doH1 = (t >= 2);
    const s16x8* pL = (const s16x8*)lB01;
    const s16x8* pU = (const s16x8*)uni;

    s16x8 Ab0[6], Ab1[6];
    {
      size_t fb = ((size_t)(wid * 2) * 8 + 0) * 512 + lane * 8;
      Ab0[0] = *(const s16x8*)(p0 + fb);
      Ab0[1] = *(const s16x8*)(p0 + fb + SPOFF);
      Ab0[2] = *(const s16x8*)(p0 + fb + 2 * SPOFF);
      if (doH1) {
        Ab0[3] = *(const s16x8*)(p1 + fb);
        Ab0[4] = *(const s16x8*)(p1 + fb + SPOFF);
        Ab0[5] = *(const s16x8*)(p1 + fb + 2 * SPOFF);
      }
    }

#pragma unroll 1
    for (int kt = 0; kt < 8; kt++) {
      s16x8 bL0s0[2], bL0s1[2], bL0s2[2], bIs0[2], bIs1[2], bIs2[2], bHs0[2], bHs1[2], bHs2[2];
#pragma unroll
      for (int u = 0; u < 2; u++) {
        if (MODE == 1) {
          bL0s0[u] = pL[(((u * 2 + 0) * 8 + kt) * 2 + 0) * 64 + lane];
          bL0s1[u] = pL[(((u * 2 + 0) * 8 + kt) * 2 + 1) * 64 + lane];
          bL0s2[u] = pU[((u * 5 + 0) * 8 + kt) * 64 + lane];
        }
        bIs0[u] = pL[(((u * 2 + 1) * 8 + kt) * 2 + 0) * 64 + lane];
        bIs1[u] = pL[(((u * 2 + 1) * 8 + kt) * 2 + 1) * 64 + lane];
        bIs2[u] = pU[((u * 5 + 1) * 8 + kt) * 64 + lane];
        if (doH1) {
          bHs0[u] = pU[((u * 5 + 2) * 8 + kt) * 64 + lane];
          bHs1[u] = pU[((u * 5 + 3) * 8 + kt) * 64 + lane];
          bHs2[u] = pU[((u * 5 + 4) * 8 + kt) * 64 + lane];
        }
      }
#pragma unroll
      for (int i = 0; i < 2; i++) {
        s16x8* cur = (i & 1) ? Ab1 : Ab0;
        s16x8* nxt = (i & 1) ? Ab0 : Ab1;
        int nkt = (i < 1) ? kt : kt + 1;
        int ni = (i < 1) ? 1 : 0;
        if (nkt < 8) {
          size_t fb = ((size_t)(wid * 2 + ni) * 8 + nkt) * 512 + lane * 8;
          nxt[0] = *(const s16x8*)(p0 + fb);
          nxt[1] = *(const s16x8*)(p0 + fb + SPOFF);
          nxt[2] = *(const s16x8*)(p0 + fb + 2 * SPOFF);
          if (doH1) {
            nxt[3] = *(const s16x8*)(p1 + fb);
            nxt[4] = *(const s16x8*)(p1 + fb + SPOFF);
            nxt[5] = *(const s16x8*)(p1 + fb + 2 * SPOFF);
          }
        }
        s16x8 a0 = cur[0], a1 = cur[1], a2 = cur[2];
#pragma unroll
        for (int u = 0; u < 2; u++) {
          if (MODE == 1) {
            aL0[i][u] = __builtin_amdgcn_mfma_f32_16x16x32_bf16(a0, bL0s0[u], aL0[i][u], 0, 0, 0);
            aL0[i][u] = __builtin_amdgcn_mfma_f32_16x16x32_bf16(a0, bL0s1[u], aL0[i][u], 0, 0, 0);
            aL0[i][u] = __builtin_amdgcn_mfma_f32_16x16x32_bf16(a1, bL0s0[u], aL0[i][u], 0, 0, 0);
            aL0[i][u] = __builtin_amdgcn_mfma_f32_16x16x32_bf16(a1, bL0s1[u], aL0[i][u], 0, 0, 0);
            aL0[i][u] = __builtin_amdgcn_mfma_f32_16x16x32_bf16(a0, bL0s2[u], aL0[i][u], 0, 0, 0);
            aL0[i][u] = __builtin_amdgcn_mfma_f32_16x16x32_bf16(a2, bL0s0[u], aL0[i][u], 0, 0, 0);
          }
          aL1[i][u] = __builtin_amdgcn_mfma_f32_16x16x32_bf16(a0, bIs0[u], aL1[i][u], 0, 0, 0);
          aL1[i][u] = __builtin_amdgcn_mfma_f32_16x16x32_bf16(a0, bIs1[u], aL1[i][u], 0, 0, 0);
          aL1[i][u] = __builtin_amdgcn_mfma_f32_16x16x32_bf16(a1, bIs0[u], aL1[i][u], 0, 0, 0);
          aL1[i][u] = __builtin_amdgcn_mfma_f32_16x16x32_bf16(a1, bIs1[u], aL1[i][u], 0, 0, 0);
          aL1[i][u] = __builtin_amdgcn_mfma_f32_16x16x32_bf16(a0, bIs2[u], aL1[i][u], 0, 0, 0);
          aL1[i][u] = __builtin_amdgcn_mfma_f32_16x16x32_bf16(a2, bIs0[u], aL1[i][u], 0, 0, 0);
          if (doH1) {
            s16x8 c0 = cur[3], c1 = cur[4], c2 = cur[5];
            aL1[i][u] = __builtin_amdgcn_mfma_f32_16x16x32_bf16(c0, bHs0[u], aL1[i][u], 0, 0, 0);
            aL1[i][u] = __builtin_amdgcn_mfma_f32_16x16x32_bf16(c0, bHs1[u], aL1[i][u], 0, 0, 0);
            aL1[i][u] = __builtin_amdgcn_mfma_f32_16x16x32_bf16(c1, bHs0[u], aL1[i][u], 0, 0, 0);
            aL1[i][u] = __builtin_amdgcn_mfma_f32_16x16x32_bf16(c1, bHs1[u], aL1[i][u], 0, 0, 0);
            aL1[i][u] = __builtin_amdgcn_mfma_f32_16x16x32_bf16(c0, bHs2[u], aL1[i][u], 0, 0, 0);
            aL1[i][u] = __builtin_amdgcn_mfma_f32_16x16x32_bf16(c2, bHs0[u], aL1[i][u], 0, 0, 0);
          }
        }
      }
    }
  }
  __syncthreads();

  float* c0w = wsm + OFF_C0;
  float* c1w = wsm + OFF_C1;
  const int ugl = tid >> 8;
  const int mloc = tid & 255;
  const int m = mb + mloc;
  const int ug = ugc * 2 + ugl;
  const int mtc = mloc >> 4, mrowc = mloc & 15;
  const int ktw = ug >> 3;
  const int lgw = (ug & 7) >> 1;
  const int ebase = (ug * 4) & 7;
  const int lww = lgw * 16 + mrowc;
  const size_t fo = ((size_t)mtc * 8 + ktw) * 512 + lww * 8 + ebase;

  // ================= L0 phase =================
  if (MODE <= 1) {
    if (MODE == 1) {
      int col = lane & 15, rb2 = (lane >> 4) * 4;
#pragma unroll
      for (int i = 0; i < 2; i++)
#pragma unroll
        for (int u = 0; u < 2; u++)
#pragma unroll
          for (int j = 0; j < 4; j++)
            gbuf[((wid * 2 + i) * 16 + rb2 + j) * GBS2 + u * 16 + col] = aL0[i][u][j];
    }
    __syncthreads();
    float zr[16];
#pragma unroll
    for (int f4 = 0; f4 < 4; f4++)
      *(float4*)&zr[f4 * 4] = *(const float4*)&z[(size_t)m * 1024 + t * 16 + f4 * 4];
    float g16[16];
#pragma unroll
    for (int gg = 0; gg < 16; gg++)
      g16[gg] = lbias[ugl * 32 + gg] + ((MODE == 1) ? gbuf[mloc * GBS2 + ugl * 16 + gg] : 0.0f);
    const float* lzu = lz + ugl * 256;
#pragma unroll
    for (int f = 0; f < 16; f++) {
      float zv = zr[f];
      float4 w0 = *(const float4*)&lzu[f * 16 + 0];
      float4 w1 = *(const float4*)&lzu[f * 16 + 4];
      float4 w2 = *(const float4*)&lzu[f * 16 + 8];
      float4 w3 = *(const float4*)&lzu[f * 16 + 12];
      g16[0] = fmaf(zv, w0.x, g16[0]);  g16[1] = fmaf(zv, w0.y, g16[1]);
      g16[2] = fmaf(zv, w0.z, g16[2]);  g16[3] = fmaf(zv, w0.w, g16[3]);
      g16[4] = fmaf(zv, w1.x, g16[4]);  g16[5] = fmaf(zv, w1.y, g16[5]);
      g16[6] = fmaf(zv, w1.z, g16[6]);  g16[7] = fmaf(zv, w1.w, g16[7]);
      g16[8] = fmaf(zv, w2.x, g16[8]);  g16[9] = fmaf(zv, w2.y, g16[9]);
      g16[10] = fmaf(zv, w2.z, g16[10]); g16[11] = fmaf(zv, w2.w, g16[11]);
      g16[12] = fmaf(zv, w3.x, g16[12]); g16[13] = fmaf(zv, w3.y, g16[13]);
      g16[14] = fmaf(zv, w3.z, g16[14]); g16[15] = fmaf(zv, w3.w, g16[15]);
    }
    unsigned short* wp = (unsigned short*)(wsm + OFF_H0P) +
                         ((size_t)(t & 1) * 8 + rg) * PANEL_US;
    short sp0[4], sp1[4], sp2[4];
#pragma unroll
    for (int ul = 0; ul < 4; ul++) {
      int u = ug * 4 + ul;
      size_t cidx = (size_t)u * 2048 + m;
      float cold = (MODE == 1) ? c0w[cidx] : 0.0f;
      float cn, hn;
      cell1s(g16[ul * 4 + 0], g16[ul * 4 + 1], g16[ul * 4 + 2], g16[ul * 4 + 3], cold, &cn, &hn);
      c0w[cidx] = cn;
      unsigned short s0 = bf16_trunc(hn);
      float r1 = hn - bf16_tof(s0);
      unsigned short s1 = bf16_trunc(r1);
      unsigned short s2 = bf16_trunc(r1 - bf16_tof(s1));
      sp0[ul] = (short)s0; sp1[ul] = (short)s1; sp2[ul] = (short)s2;
    }
    *(short4*)&wp[fo]             = make_short4(sp0[0], sp0[1], sp0[2], sp0[3]);
    *(short4*)&wp[fo + SPOFF]     = make_short4(sp1[0], sp1[1], sp1[2], sp1[3]);
    *(short4*)&wp[fo + 2 * SPOFF] = make_short4(sp2[0], sp2[1], sp2[2], sp2[3]);
    __syncthreads();
  }

  // ================= L1 phase =================
  if (MODE >= 1) {
    {
      int col = lane & 15, rb2 = (lane >> 4) * 4;
#pragma unroll
      for (int i = 0; i < 2; i++)
#pragma unroll
        for (int u = 0; u < 2; u++)
#pragma unroll
          for (int j = 0; j < 4; j++)
            gbuf[((wid * 2 + i) * 16 + rb2 + j) * GBS2 + u * 16 + col] = aL1[i][u][j];
    }
    __syncthreads();
    int slot = (t - 1) & 15;
    unsigned short* rp = (unsigned short*)(wsm + OFF_RINGF) +
                         ((size_t)slot * 8 + rg) * PANEL_US;
    short sp0[4], sp1[4], sp2[4];
#pragma unroll
    for (int ul = 0; ul < 4; ul++) {
      float gi = lbias[ugl * 32 + 16 + ul * 4 + 0] + gbuf[mloc * GBS2 + ugl * 16 + ul * 4 + 0];
      float gf = lbias[ugl * 32 + 16 + ul * 4 + 1] + gbuf[mloc * GBS2 + ugl * 16 + ul * 4 + 1];
      float gt = lbias[ugl * 32 + 16 + ul * 4 + 2] + gbuf[mloc * GBS2 + ugl * 16 + ul * 4 + 2];
      float go = lbias[ugl * 32 + 16 + ul * 4 + 3] + gbuf[mloc * GBS2 + ugl * 16 + ul * 4 + 3];
      int u = ug * 4 + ul;
      size_t cidx = (size_t)u * 2048 + m;
      float cold = (t >= 2) ? c1w[cidx] : 0.0f;
      float cn, hn;
      cell1s(gi, gf, gt, go, cold, &cn, &hn);
      c1w[cidx] = cn;
      unsigned short s0 = bf16_trunc(hn);
      float r1v = hn - bf16_tof(s0);
      unsigned short s1 = bf16_trunc(r1v);
      unsigned short s2 = bf16_trunc(r1v - bf16_tof(s1));
      sp0[ul] = (short)s0; sp1[ul] = (short)s1; sp2[ul] = (short)s2;
    }
    *(short4*)&rp[fo]             = make_short4(sp0[0], sp0[1], sp0[2], sp0[3]);
    *(short4*)&rp[fo + SPOFF]     = make_short4(sp1[0], sp1[1], sp1[2], sp1[3]);
    *(short4*)&rp[fo + 2 * SPOFF] = make_short4(sp2[0], sp2[1], sp2[2], sp2[3]);
  }
}

// FC GEMM (bf16x3): y[slot][m][192] = h1 . fcW^T (bias added in sampling).
// Grid 256 = (mtg2 x slot16 x rg8); 512 thr, 8 waves; wave = 1 mt, loops 3 ng x 4 nt.
__launch_bounds__(512, 2)
__global__ void vfpg_fc(const float* __restrict__ ws, float* __restrict__ wsm) {
  const int tid = threadIdx.x;
  const int rg = blockIdx.x & 7;
  const int slot = (blockIdx.x >> 3) & 15;
  const int mtg = blockIdx.x >> 7;
  const int lane = tid & 63, wid = tid >> 6;
  const int mt = mtg * 8 + wid;

  const unsigned short* pa = (const unsigned short*)(ws + OFF_RINGF) +
                             ((size_t)slot * 8 + rg) * PANEL_US;
  const unsigned short* BFC = (const unsigned short*)(ws + OFF_FCB3);
  float* y = wsm + OFF_Y + (size_t)slot * (2048 * 192) + (size_t)(rg * 256) * 192;

  const int col = lane & 15, rb2 = (lane >> 4) * 4;

#pragma unroll 1
  for (int ng = 0; ng < 3; ng++) {
    f32x4 C[4];
#pragma unroll
    for (int j = 0; j < 4; j++) C[j] = (f32x4)0.0f;
#pragma unroll 1
    for (int kt = 0; kt < 8; kt++) {
      size_t fb = ((size_t)mt * 8 + kt) * 512 + lane * 8;
      s16x8 a0 = *(const s16x8*)(pa + fb);
      s16x8 a1 = *(const s16x8*)(pa + fb + SPOFF);
      s16x8 a2 = *(const s16x8*)(pa + fb + 2 * SPOFF);
#pragma unroll
      for (int n4 = 0; n4 < 4; n4++) {
        int nt = ng * 4 + n4;
        const unsigned short* bp = BFC + (size_t)(nt * 8 + kt) * (3 * 512) + lane * 8;
        s16x8 b0 = *(const s16x8*)(bp);
        s16x8 b1 = *(const s16x8*)(bp + 512);
        s16x8 b2 = *(const s16x8*)(bp + 1024);
        C[n4] = __builtin_amdgcn_mfma_f32_16x16x32_bf16(a0, b0, C[n4], 0, 0, 0);
        C[n4] = __builtin_amdgcn_mfma_f32_16x16x32_bf16(a0, b1, C[n4], 0, 0, 0);
        C[n4] = __builtin_amdgcn_mfma_f32_16x16x32_bf16(a1, b0, C[n4], 0, 0, 0);
        C[n4] = __builtin_amdgcn_mfma_f32_16x16x32_bf16(a1, b1, C[n4], 0, 0, 0);
        C[n4] = __builtin_amdgcn_mfma_f32_16x16x32_bf16(a0, b2, C[n4], 0, 0, 0);
        C[n4] = __builtin_amdgcn_mfma_f32_16x16x32_bf16(a2, b0, C[n4], 0, 0, 0);
      }
    }
#pragma unroll
    for (int n4 = 0; n4 < 4; n4++) {
      int c = (ng * 4 + n4) * 16 + col;
#pragma unroll
      for (int j = 0; j < 4; j++) {
        int mrow = mt * 16 + rb2 + j;
        y[(size_t)mrow * 192 + c] = C[n4][j];
      }
    }
  }
}

// Sampling: wave = one (slot,m) row; reads y, adds exact fp32 bias, runs MDN head.
__launch_bounds__(512, 2)
__global__ void vfpg_samp(const float* __restrict__ ws, const float* __restrict__ fcb,
                          float* __restrict__ out, int tbase,
                          uint32_t k1a, uint32_t k1b, uint32_t k2a, uint32_t k2b) {
  const int tid = threadIdx.x;
  const int lane = tid & 63, wid = tid >> 6;
  const int ridx = blockIdx.x * 8 + wid;       // 0..32767 = slot*2048 + m
  const int slot = ridx >> 11;
  const int m = ridx & 2047;

  const float* yrow = ws + OFF_Y + (size_t)ridx * 192;
  float yg = yrow[lane] + fcb[lane];
  float ys = yrow[64 + lane] + fcb[64 + lane];
  float ym = yrow[128 + lane] + fcb[128 + lane];

  uint32_t rid = (uint32_t)m * Tdim + (uint32_t)(tbase + slot);
  mdn_head(yg, ys, ym, lane, rid, k1a, k1b, k2a, k2b, out);
}

extern "C" void kernel_launch(void* const* d_in, const int* in_sizes, int n_in,
                              void* d_out, int out_size, void* d_ws, size_t ws_size,
                              hipStream_t stream) {
  const float* z    = (const float*)d_in[0];
  const float* Wih0 = (const float*)d_in[1];
  const float* Whh0 = (const float*)d_in[2];
  const float* bih0 = (const float*)d_in[3];
  const float* bhh0 = (const float*)d_in[4];
  const float* Wih1 = (const float*)d_in[5];
  const float* Whh1 = (const float*)d_in[6];
  const float* bih1 = (const float*)d_in[7];
  const float* bhh1 = (const float*)d_in[8];
  const float* fcW  = (const float*)d_in[9];
  const float* fcb  = (const float*)d_in[10];
  float* ws = (float*)d_ws;
  float* out = (float*)d_out;

  if (ws_size < (size_t)WS_TOT * sizeof(float)) return;  // ~99.7 MB (<137.7 proven)

  vfpg_prep<<<dim3(512), dim3(256), 0, stream>>>(
      Wih0, Whh0, Wih1, Whh1, fcW, bih0, bhh0, bih1, bhh1, ws);

  uint32_t k1a, k1b, k2a, k2b;
  tf2x32(0u, 42u, 0u, 0u, &k1a, &k1b);
  tf2x32(0u, 42u, 0u, 1u, &k2a, &k2b);

  vfpg_step<0><<<dim3(256), dim3(512), 0, stream>>>(z, ws, ws, 0);
  for (int t = 1; t <= 63; t++) {
    vfpg_step<1><<<dim3(256), dim3(512), 0, stream>>>(z, ws, ws, t);
    if (t == 16 || t == 32 || t == 48) {
      vfpg_fc<<<dim3(256), dim3(512), 0, stream>>>(ws, ws);
      vfpg_samp<<<dim3(4096), dim3(512), 0, stream>>>(ws, fcb, out, t - 16,
                                                      k1a, k1b, k2a, k2b);
    }
  }
  vfpg_step<2><<<dim3(256), dim3(512), 0, stream>>>(z, ws, ws, 64);
  vfpg_fc<<<dim3(256), dim3(512), 0, stream>>>(ws, ws);
  vfpg_samp<<<dim3(4096), dim3(512), 0, stream>>>(ws, fcb, out, 48, k1a, k1b, k2a, k2b);
}

// Round 17
// 1927.766 us; speedup vs baseline: 4.0884x; 1.0022x over previous
//
#include <hip/hip_runtime.h>
#include <stdint.h>
#include <stddef.h>

// Problem dims
#define Mdim 2048
#define Tdim 64
#define INdim 16
#define Hdim 256
#define NCdim 64
#define NUG 64
#define HSLAB (256 * 2048)
#define RSLOTS 16

typedef __attribute__((ext_vector_type(8))) short s16x8;
typedef __attribute__((ext_vector_type(4))) float f32x4;

// Panel (per tbuf/slot, per rg): [sp3][mt16][kt8][512] bf16  -> 196608 ushorts
#define PANEL_US (3 * 16 * 8 * 512)
#define SPOFF 65536   // 16*8*512, split stride in ushorts
// BFRAG per ug: [cls3][kt8][sp3][512] bf16 -> 36864 ushorts
#define BFRAG_US (3 * 8 * 3 * 512)

// ws float offsets
#define OFF_BFRAG 0                                    // 64 * 36864 us = 1179648 fl
#define OFF_WZ    1179648                              // [64][16 k][16 g] fp32
#define OFF_BB    (OFF_WZ + 64 * 256)                  // [64][32]
#define OFF_WFCP  (OFF_BB + 64 * 32)                   // (unused, reserved)
#define OFF_H0P   (OFF_WFCP + 256 * 64 * 4)            // [2 tbuf][8 rg] panels
#define OFF_C0    (OFF_H0P + 1572864)
#define OFF_C1    (OFF_C0 + HSLAB)
#define OFF_RINGF (OFF_C1 + HSLAB)                     // [16 slot][8 rg] panels
#define OFF_Y     (OFF_RINGF + 12582912)               // y[16 slot][2048 m][192] fp32
#define OFF_FCB3  (OFF_Y + RSLOTS * HSLAB)             // FC B-frags bf16x3: 73728 fl
#define WS_TOT    (OFF_FCB3 + 73728)                   // 24930304 fl = 99.7 MB

#define ROTL32(v, s) (((v) << (s)) | ((v) >> (32 - (s))))

__host__ __device__ inline void tf2x32(uint32_t k0, uint32_t k1, uint32_t x0, uint32_t x1,
                                       uint32_t* o0, uint32_t* o1) {
  uint32_t ks2 = k0 ^ k1 ^ 0x1BD11BDAu;
  x0 += k0; x1 += k1;
  x0 += x1; x1 = ROTL32(x1, 13); x1 ^= x0;
  x0 += x1; x1 = ROTL32(x1, 15); x1 ^= x0;
  x0 += x1; x1 = ROTL32(x1, 26); x1 ^= x0;
  x0 += x1; x1 = ROTL32(x1, 6);  x1 ^= x0;
  x0 += k1; x1 += ks2 + 1u;
  x0 += x1; x1 = ROTL32(x1, 17); x1 ^= x0;
  x0 += x1; x1 = ROTL32(x1, 29); x1 ^= x0;
  x0 += x1; x1 = ROTL32(x1, 16); x1 ^= x0;
  x0 += x1; x1 = ROTL32(x1, 24); x1 ^= x0;
  x0 += ks2; x1 += k0 + 2u;
  x0 += x1; x1 = ROTL32(x1, 13); x1 ^= x0;
  x0 += x1; x1 = ROTL32(x1, 15); x1 ^= x0;
  x0 += x1; x1 = ROTL32(x1, 26); x1 ^= x0;
  x0 += x1; x1 = ROTL32(x1, 6);  x1 ^= x0;
  x0 += k0; x1 += k1 + 3u;
  x0 += x1; x1 = ROTL32(x1, 17); x1 ^= x0;
  x0 += x1; x1 = ROTL32(x1, 29); x1 ^= x0;
  x0 += x1; x1 = ROTL32(x1, 16); x1 ^= x0;
  x0 += x1; x1 = ROTL32(x1, 24); x1 ^= x0;
  x0 += k1; x1 += ks2 + 4u;
  x0 += x1; x1 = ROTL32(x1, 13); x1 ^= x0;
  x0 += x1; x1 = ROTL32(x1, 15); x1 ^= x0;
  x0 += x1; x1 = ROTL32(x1, 26); x1 ^= x0;
  x0 += x1; x1 = ROTL32(x1, 6);  x1 ^= x0;
  x0 += ks2; x1 += k0 + 5u;
  *o0 = x0; *o1 = x1;
}

__device__ inline uint32_t random_bits32(uint32_t ka, uint32_t kb, uint32_t p) {
  uint32_t a, b;
  tf2x32(ka, kb, 0u, p, &a, &b);
  return a ^ b;
}

__device__ inline float bits_to_u01(uint32_t bits) {
  return __uint_as_float((bits >> 9) | 0x3f800000u) - 1.0f;
}

__device__ inline float sigm_fast(float x) { return 1.0f / (1.0f + __expf(-x)); }

__device__ inline float erfinv_f32(float x) {
  float w = -log1pf(-x * x);
  float p;
  if (w < 5.0f) {
    w -= 2.5f;
    p = 2.81022636e-08f;
    p = fmaf(p, w, 3.43273939e-07f);
    p = fmaf(p, w, -3.5233877e-06f);
    p = fmaf(p, w, -4.39150654e-06f);
    p = fmaf(p, w, 0.00021858087f);
    p = fmaf(p, w, -0.00125372503f);
    p = fmaf(p, w, -0.00417768164f);
    p = fmaf(p, w, 0.246640727f);
    p = fmaf(p, w, 1.50140941f);
  } else {
    w = sqrtf(w) - 3.0f;
    p = -0.000200214257f;
    p = fmaf(p, w, 0.000100950558f);
    p = fmaf(p, w, 0.00134934322f);
    p = fmaf(p, w, -0.00367342844f);
    p = fmaf(p, w, 0.00573950773f);
    p = fmaf(p, w, -0.0076224613f);
    p = fmaf(p, w, 0.00943887047f);
    p = fmaf(p, w, 1.00167406f);
    p = fmaf(p, w, 2.83297682f);
  }
  return p * x;
}

__device__ inline void mdn_head(float yg, float ysg, float ym, int lane, uint32_t rid,
                                uint32_t k1a, uint32_t k1b, uint32_t k2a, uint32_t k2b,
                                float* __restrict__ out) {
  uint32_t pp = rid * (uint32_t)NCdim + (uint32_t)lane;
  uint32_t bits = random_bits32(k1a, k1b, pp);
  float u01 = bits_to_u01(bits);
  const float tinyf = 1.17549435e-38f;
  float uu = fmaxf(tinyf, u01 + tinyf);
  float gum = -logf(-logf(uu));
  float val = gum + yg;
  int idx = lane;
#pragma unroll
  for (int s = 1; s < 64; s <<= 1) {
    float ov = __shfl_xor(val, s);
    int oi = __shfl_xor(idx, s);
    if (ov > val || (ov == val && oi < idx)) { val = ov; idx = oi; }
  }
  float mu_sel = __shfl(ym, idx);
  float s_sel = __shfl(ysg, idx);

  uint32_t ebits = random_bits32(k2a, k2b, rid);
  float ue = bits_to_u01(ebits);
  const float lo = __uint_as_float(0xBF7FFFFFu);
  float un2 = fmaxf(lo, ue * 2.0f + lo);
  float eps = 1.41421356f * erfinv_f32(un2);

  float x_pred = mu_sel + expf(s_sel) * eps;

  float mx = yg;
#pragma unroll
  for (int s = 1; s < 64; s <<= 1) mx = fmaxf(mx, __shfl_xor(mx, s));
  float se = expf(yg - mx);
#pragma unroll
  for (int s = 1; s < 64; s <<= 1) se += __shfl_xor(se, s);
  float d = x_pred - ym;
  float lk = -0.5f * d * d - 66.0f * ysg - 58.812066f;
  float ts = expf(yg - mx + lk);
#pragma unroll
  for (int s = 1; s < 64; s <<= 1) ts += __shfl_xor(ts, s);
  float prob = ts / se;

  if (lane == 0) {
    out[rid] = x_pred;
    out[(size_t)Mdim * Tdim + rid] = prob;
  }
}

__device__ __host__ inline unsigned short bf16_trunc(float x) {
  union { float f; uint32_t u; } c; c.f = x;
  return (unsigned short)(c.u >> 16);
}
__device__ __host__ inline float bf16_tof(unsigned short s) {
  union { float f; uint32_t u; } c; c.u = ((uint32_t)s) << 16;
  return c.f;
}

// Prep: pack LSTM B-frags (bf16x3), WZ, biases, FC B-frags (bf16x3). (unchanged)
__global__ void vfpg_prep(const float* __restrict__ Wih0, const float* __restrict__ Whh0,
                          const float* __restrict__ Wih1, const float* __restrict__ Whh1,
                          const float* __restrict__ fcW, const float* __restrict__ bih0,
                          const float* __restrict__ bhh0, const float* __restrict__ bih1,
                          const float* __restrict__ bhh1, float* __restrict__ ws) {
  int i0 = blockIdx.x * blockDim.x + threadIdx.x;
  int n = blockDim.x * gridDim.x;
  unsigned short* BF = (unsigned short*)(ws + OFF_BFRAG);
  for (int i = i0; i < 64 * 3 * 8 * 512; i += n) {
    int ug = i / 12288, r = i % 12288;
    int cls = r / 4096, r2 = r % 4096;
    int kt = r2 >> 9, pos = r2 & 511;
    int l = pos >> 3, e = pos & 7;
    int n16 = l & 15, lg = l >> 4;
    int k = kt * 32 + lg * 8 + e;
    int ul = n16 >> 2, ty = n16 & 3;
    int gd = ty * 256 + ug * 4 + ul;
    const float* W = (cls == 0) ? Whh0 : ((cls == 1) ? Wih1 : Whh1);
    float w = W[gd * 256 + k];
    unsigned short s0 = bf16_trunc(w);
    float r1 = w - bf16_tof(s0);
    unsigned short s1 = bf16_trunc(r1);
    unsigned short s2 = bf16_trunc(r1 - bf16_tof(s1));
    size_t base = ((size_t)(ug * 3 + cls) * 8 + kt) * (3 * 512) + pos;
    BF[base] = s0;
    BF[base + 512] = s1;
    BF[base + 1024] = s2;
  }
  for (int i = i0; i < 64 * 256; i += n) {
    int ug = i >> 8, k = (i >> 4) & 15, g = i & 15;
    int gd = (g & 3) * 256 + ug * 4 + (g >> 2);
    ws[OFF_WZ + i] = Wih0[gd * INdim + k];
  }
  for (int i = i0; i < 64 * 32; i += n) {
    int ug = i >> 5, r = i & 31, g = r & 15;
    int gd = (g & 3) * 256 + ug * 4 + (g >> 2);
    ws[OFF_BB + i] = (r < 16) ? (bih0[gd] + bhh0[gd]) : (bih1[gd] + bhh1[gd]);
  }
  unsigned short* BFC = (unsigned short*)(ws + OFF_FCB3);
  for (int i = i0; i < 12 * 8 * 512; i += n) {
    int ntkt = i >> 9, pos = i & 511;
    int nt = ntkt >> 3, kt = ntkt & 7;
    int l = pos >> 3, e = pos & 7;
    int c = nt * 16 + (l & 15);
    int k = kt * 32 + (l >> 4) * 8 + e;
    float w = fcW[c * Hdim + k];
    unsigned short s0 = bf16_trunc(w);
    float r1 = w - bf16_tof(s0);
    unsigned short s1 = bf16_trunc(r1);
    unsigned short s2 = bf16_trunc(r1 - bf16_tof(s1));
    size_t base = (size_t)ntkt * (3 * 512) + pos;
    BFC[base] = s0;
    BFC[base + 512] = s1;
    BFC[base + 1024] = s2;
  }
}

__device__ inline void cell1s(float gi, float gf, float gg, float go, float cold,
                              float* cn, float* hn) {
  float si = sigm_fast(gi), sf = sigm_fast(gf);
  float tg = fmaf(2.0f, sigm_fast(2.0f * gg), -1.0f);
  float so = sigm_fast(go);
  float cc = fmaf(sf, cold, si * tg);
  *cn = cc;
  *hn = so * fmaf(2.0f, sigm_fast(2.0f * cc), -1.0f);
}

#define GBS3 66   // merged gbuf row stride: 64 gate cols (L0:0-31, L1:32-63) + 2 pad

// Launch t: layer0 step t + layer1 step t-1. MODE 0: t=0; 1: 1..63; 2: t=64.
// Grid 256 = 8 rg x 32 ugc (2 ugs/block). 512 thr, 8 waves; wave = 2 mt x 2 ugs.
// Merged staging: both layers' gates staged in one barrier pair, cells fused.
template <int MODE>
__launch_bounds__(512, 2)
__global__ void vfpg_step(const float* __restrict__ z, const float* __restrict__ ws,
                          float* __restrict__ wsm, int t) {
  __shared__ unsigned short lB01[2 * 2 * 8 * 2 * 512];  // 64 KB
  __shared__ __align__(16) unsigned char uni[81920];    // 80 KB: B-s2/hh1 region -> gbuf
  __shared__ float lz[2 * 256];
  __shared__ float lbias[64];

  const int tid = threadIdx.x;
  const int rg = blockIdx.x & 7, ugc = blockIdx.x >> 3;
  const int mb = rg * 256;
  const int lane = tid & 63, wid = tid >> 6;
  float* gbuf = (float*)uni;

  {
    const unsigned short* BF = (const unsigned short*)(ws + OFF_BFRAG);
    const unsigned short* BG0 = BF + (size_t)(ugc * 2 + 0) * BFRAG_US;
    const unsigned short* BG1 = BF + (size_t)(ugc * 2 + 1) * BFRAG_US;
    for (int i = tid; i < 2 * 4608; i += 512) {
      int ugl = i / 4608;
      int r = i % 4608;
      int cls = r / 1536;
      int r2 = r % 1536;
      int kt = r2 / 192;
      int sp = (r2 / 64) % 3;
      int v = r2 & 63;
      const unsigned short* src = (ugl ? BG1 : BG0) + ((size_t)(cls * 8 + kt) * 3 + sp) * 512 + v * 8;
      s16x8 val = *(const s16x8*)src;
      if (cls < 2 && sp < 2) {
        ((s16x8*)lB01)[((((ugl * 2 + cls) * 8 + kt) * 2 + sp)) * 64 + v] = val;
      } else {
        int str = (cls == 2) ? (2 + sp) : cls;
        ((s16x8*)uni)[(((ugl * 5 + str) * 8 + kt)) * 64 + v] = val;
      }
    }
    if (tid < 128) ((float4*)lz)[tid] = ((const float4*)(ws + OFF_WZ + (ugc * 2) * 256))[tid];
    if (tid < 64) lbias[tid] = ws[OFF_BB + (ugc * 2) * 32 + tid];
  }
  __syncthreads();

  f32x4 aL0[2][2], aL1[2][2];
#pragma unroll
  for (int i = 0; i < 2; i++)
#pragma unroll
    for (int u = 0; u < 2; u++) { aL0[i][u] = (f32x4)0.0f; aL1[i][u] = (f32x4)0.0f; }

  if (MODE >= 1) {
    const unsigned short* p0 = (const unsigned short*)(ws + OFF_H0P) +
                               ((size_t)((t - 1) & 1) * 8 + rg) * PANEL_US;
    const unsigned short* p1 = (const unsigned short*)(ws + OFF_RINGF) +
                               ((size_t)((t - 2) & 15) * 8 + rg) * PANEL_US;
    const bool doH1 = (t >= 2);
    const s16x8* pL = (const s16x8*)lB01;
    const s16x8* pU = (const s16x8*)uni;

    s16x8 Ab0[6], Ab1[6];
    {
      size_t fb = ((size_t)(wid * 2) * 8 + 0) * 512 + lane * 8;
      Ab0[0] = *(const s16x8*)(p0 + fb);
      Ab0[1] = *(const s16x8*)(p0 + fb + SPOFF);
      Ab0[2] = *(const s16x8*)(p0 + fb + 2 * SPOFF);
      if (doH1) {
        Ab0[3] = *(const s16x8*)(p1 + fb);
        Ab0[4] = *(const s16x8*)(p1 + fb + SPOFF);
        Ab0[5] = *(const s16x8*)(p1 + fb + 2 * SPOFF);
      }
    }

#pragma unroll 1
    for (int kt = 0; kt < 8; kt++) {
      s16x8 bL0s0[2], bL0s1[2], bL0s2[2], bIs0[2], bIs1[2], bIs2[2], bHs0[2], bHs1[2], bHs2[2];
#pragma unroll
      for (int u = 0; u < 2; u++) {
        if (MODE == 1) {
          bL0s0[u] = pL[(((u * 2 + 0) * 8 + kt) * 2 + 0) * 64 + lane];
          bL0s1[u] = pL[(((u * 2 + 0) * 8 + kt) * 2 + 1) * 64 + lane];
          bL0s2[u] = pU[((u * 5 + 0) * 8 + kt) * 64 + lane];
        }
        bIs0[u] = pL[(((u * 2 + 1) * 8 + kt) * 2 + 0) * 64 + lane];
        bIs1[u] = pL[(((u * 2 + 1) * 8 + kt) * 2 + 1) * 64 + lane];
        bIs2[u] = pU[((u * 5 + 1) * 8 + kt) * 64 + lane];
        if (doH1) {
          bHs0[u] = pU[((u * 5 + 2) * 8 + kt) * 64 + lane];
          bHs1[u] = pU[((u * 5 + 3) * 8 + kt) * 64 + lane];
          bHs2[u] = pU[((u * 5 + 4) * 8 + kt) * 64 + lane];
        }
      }
#pragma unroll
      for (int i = 0; i < 2; i++) {
        s16x8* cur = (i & 1) ? Ab1 : Ab0;
        s16x8* nxt = (i & 1) ? Ab0 : Ab1;
        int nkt = (i < 1) ? kt : kt + 1;
        int ni = (i < 1) ? 1 : 0;
        if (nkt < 8) {
          size_t fb = ((size_t)(wid * 2 + ni) * 8 + nkt) * 512 + lane * 8;
          nxt[0] = *(const s16x8*)(p0 + fb);
          nxt[1] = *(const s16x8*)(p0 + fb + SPOFF);
          nxt[2] = *(const s16x8*)(p0 + fb + 2 * SPOFF);
          if (doH1) {
            nxt[3] = *(const s16x8*)(p1 + fb);
            nxt[4] = *(const s16x8*)(p1 + fb + SPOFF);
            nxt[5] = *(const s16x8*)(p1 + fb + 2 * SPOFF);
          }
        }
        s16x8 a0 = cur[0], a1 = cur[1], a2 = cur[2];
#pragma unroll
        for (int u = 0; u < 2; u++) {
          if (MODE == 1) {
            aL0[i][u] = __builtin_amdgcn_mfma_f32_16x16x32_bf16(a0, bL0s0[u], aL0[i][u], 0, 0, 0);
            aL0[i][u] = __builtin_amdgcn_mfma_f32_16x16x32_bf16(a0, bL0s1[u], aL0[i][u], 0, 0, 0);
            aL0[i][u] = __builtin_amdgcn_mfma_f32_16x16x32_bf16(a1, bL0s0[u], aL0[i][u], 0, 0, 0);
            aL0[i][u] = __builtin_amdgcn_mfma_f32_16x16x32_bf16(a1, bL0s1[u], aL0[i][u], 0, 0, 0);
            aL0[i][u] = __builtin_amdgcn_mfma_f32_16x16x32_bf16(a0, bL0s2[u], aL0[i][u], 0, 0, 0);
            aL0[i][u] = __builtin_amdgcn_mfma_f32_16x16x32_bf16(a2, bL0s0[u], aL0[i][u], 0, 0, 0);
          }
          aL1[i][u] = __builtin_amdgcn_mfma_f32_16x16x32_bf16(a0, bIs0[u], aL1[i][u], 0, 0, 0);
          aL1[i][u] = __builtin_amdgcn_mfma_f32_16x16x32_bf16(a0, bIs1[u], aL1[i][u], 0, 0, 0);
          aL1[i][u] = __builtin_amdgcn_mfma_f32_16x16x32_bf16(a1, bIs0[u], aL1[i][u], 0, 0, 0);
          aL1[i][u] = __builtin_amdgcn_mfma_f32_16x16x32_bf16(a1, bIs1[u], aL1[i][u], 0, 0, 0);
          aL1[i][u] = __builtin_amdgcn_mfma_f32_16x16x32_bf16(a0, bIs2[u], aL1[i][u], 0, 0, 0);
          aL1[i][u] = __builtin_amdgcn_mfma_f32_16x16x32_bf16(a2, bIs0[u], aL1[i][u], 0, 0, 0);
          if (doH1) {
            s16x8 c0 = cur[3], c1 = cur[4], c2 = cur[5];
            aL1[i][u] = __builtin_amdgcn_mfma_f32_16x16x32_bf16(c0, bHs0[u], aL1[i][u], 0, 0, 0);
            aL1[i][u] = __builtin_amdgcn_mfma_f32_16x16x32_bf16(c0, bHs1[u], aL1[i][u], 0, 0, 0);
            aL1[i][u] = __builtin_amdgcn_mfma_f32_16x16x32_bf16(c1, bHs0[u], aL1[i][u], 0, 0, 0);
            aL1[i][u] = __builtin_amdgcn_mfma_f32_16x16x32_bf16(c1, bHs1[u], aL1[i][u], 0, 0, 0);
            aL1[i][u] = __builtin_amdgcn_mfma_f32_16x16x32_bf16(c0, bHs2[u], aL1[i][u], 0, 0, 0);
            aL1[i][u] = __builtin_amdgcn_mfma_f32_16x16x32_bf16(c2, bHs0[u], aL1[i][u], 0, 0, 0);
          }
        }
      }
    }
  }
  __syncthreads();   // all uni B-reads complete; uni becomes gbuf

  // ---- merged gate staging: both layers, one barrier pair ----
  {
    int col = lane & 15, rb2 = (lane >> 4) * 4;
#pragma unroll
    for (int i = 0; i < 2; i++)
#pragma unroll
      for (int u = 0; u < 2; u++)
#pragma unroll
        for (int j = 0; j < 4; j++) {
          int row = (wid * 2 + i) * 16 + rb2 + j;
          if (MODE == 1) gbuf[row * GBS3 + u * 16 + col] = aL0[i][u][j];
          if (MODE >= 1) gbuf[row * GBS3 + 32 + u * 16 + col] = aL1[i][u][j];
        }
  }
  __syncthreads();

  float* c0w = wsm + OFF_C0;
  float* c1w = wsm + OFF_C1;
  const int ugl = tid >> 8;
  const int mloc = tid & 255;
  const int m = mb + mloc;
  const int ug = ugc * 2 + ugl;
  const int mtc = mloc >> 4, mrowc = mloc & 15;
  const int ktw = ug >> 3;
  const int lgw = (ug & 7) >> 1;
  const int ebase = (ug * 4) & 7;
  const int lww = lgw * 16 + mrowc;
  const size_t fo = ((size_t)mtc * 8 + ktw) * 512 + lww * 8 + ebase;

  // ---- fused cell updates (L0 then L1, single phase) ----
  if (MODE <= 1) {
    float zr[16];
#pragma unroll
    for (int f4 = 0; f4 < 4; f4++)
      *(float4*)&zr[f4 * 4] = *(const float4*)&z[(size_t)m * 1024 + t * 16 + f4 * 4];
    float g16[16];
#pragma unroll
    for (int gg = 0; gg < 16; gg++)
      g16[gg] = lbias[ugl * 32 + gg] + ((MODE == 1) ? gbuf[mloc * GBS3 + ugl * 16 + gg] : 0.0f);
    const float* lzu = lz + ugl * 256;
#pragma unroll
    for (int f = 0; f < 16; f++) {
      float zv = zr[f];
      float4 w0 = *(const float4*)&lzu[f * 16 + 0];
      float4 w1 = *(const float4*)&lzu[f * 16 + 4];
      float4 w2 = *(const float4*)&lzu[f * 16 + 8];
      float4 w3 = *(const float4*)&lzu[f * 16 + 12];
      g16[0] = fmaf(zv, w0.x, g16[0]);  g16[1] = fmaf(zv, w0.y, g16[1]);
      g16[2] = fmaf(zv, w0.z, g16[2]);  g16[3] = fmaf(zv, w0.w, g16[3]);
      g16[4] = fmaf(zv, w1.x, g16[4]);  g16[5] = fmaf(zv, w1.y, g16[5]);
      g16[6] = fmaf(zv, w1.z, g16[6]);  g16[7] = fmaf(zv, w1.w, g16[7]);
      g16[8] = fmaf(zv, w2.x, g16[8]);  g16[9] = fmaf(zv, w2.y, g16[9]);
      g16[10] = fmaf(zv, w2.z, g16[10]); g16[11] = fmaf(zv, w2.w, g16[11]);
      g16[12] = fmaf(zv, w3.x, g16[12]); g16[13] = fmaf(zv, w3.y, g16[13]);
      g16[14] = fmaf(zv, w3.z, g16[14]); g16[15] = fmaf(zv, w3.w, g16[15]);
    }
    unsigned short* wp = (unsigned short*)(wsm + OFF_H0P) +
                         ((size_t)(t & 1) * 8 + rg) * PANEL_US;
    short sp0[4], sp1[4], sp2[4];
#pragma unroll
    for (int ul = 0; ul < 4; ul++) {
      int u = ug * 4 + ul;
      size_t cidx = (size_t)u * 2048 + m;
      float cold = (MODE == 1) ? c0w[cidx] : 0.0f;
      float cn, hn;
      cell1s(g16[ul * 4 + 0], g16[ul * 4 + 1], g16[ul * 4 + 2], g16[ul * 4 + 3], cold, &cn, &hn);
      c0w[cidx] = cn;
      unsigned short s0 = bf16_trunc(hn);
      float r1 = hn - bf16_tof(s0);
      unsigned short s1 = bf16_trunc(r1);
      unsigned short s2 = bf16_trunc(r1 - bf16_tof(s1));
      sp0[ul] = (short)s0; sp1[ul] = (short)s1; sp2[ul] = (short)s2;
    }
    *(short4*)&wp[fo]             = make_short4(sp0[0], sp0[1], sp0[2], sp0[3]);
    *(short4*)&wp[fo + SPOFF]     = make_short4(sp1[0], sp1[1], sp1[2], sp1[3]);
    *(short4*)&wp[fo + 2 * SPOFF] = make_short4(sp2[0], sp2[1], sp2[2], sp2[3]);
  }

  if (MODE >= 1) {
    int slot = (t - 1) & 15;
    unsigned short* rp = (unsigned short*)(wsm + OFF_RINGF) +
                         ((size_t)slot * 8 + rg) * PANEL_US;
    short sp0[4], sp1[4], sp2[4];
#pragma unroll
    for (int ul = 0; ul < 4; ul++) {
      float gi = lbias[ugl * 32 + 16 + ul * 4 + 0] + gbuf[mloc * GBS3 + 32 + ugl * 16 + ul * 4 + 0];
      float gf = lbias[ugl * 32 + 16 + ul * 4 + 1] + gbuf[mloc * GBS3 + 32 + ugl * 16 + ul * 4 + 1];
      float gt = lbias[ugl * 32 + 16 + ul * 4 + 2] + gbuf[mloc * GBS3 + 32 + ugl * 16 + ul * 4 + 2];
      float go = lbias[ugl * 32 + 16 + ul * 4 + 3] + gbuf[mloc * GBS3 + 32 + ugl * 16 + ul * 4 + 3];
      int u = ug * 4 + ul;
      size_t cidx = (size_t)u * 2048 + m;
      float cold = (t >= 2) ? c1w[cidx] : 0.0f;
      float cn, hn;
      cell1s(gi, gf, gt, go, cold, &cn, &hn);
      c1w[cidx] = cn;
      unsigned short s0 = bf16_trunc(hn);
      float r1v = hn - bf16_tof(s0);
      unsigned short s1 = bf16_trunc(r1v);
      unsigned short s2 = bf16_trunc(r1v - bf16_tof(s1));
      sp0[ul] = (short)s0; sp1[ul] = (short)s1; sp2[ul] = (short)s2;
    }
    *(short4*)&rp[fo]             = make_short4(sp0[0], sp0[1], sp0[2], sp0[3]);
    *(short4*)&rp[fo + SPOFF]     = make_short4(sp1[0], sp1[1], sp1[2], sp1[3]);
    *(short4*)&rp[fo + 2 * SPOFF] = make_short4(sp2[0], sp2[1], sp2[2], sp2[3]);
  }
}

// FC GEMM (bf16x3): y[slot][m][192] = h1 . fcW^T (bias added in sampling). (unchanged)
__launch_bounds__(512, 2)
__global__ void vfpg_fc(const float* __restrict__ ws, float* __restrict__ wsm) {
  const int tid = threadIdx.x;
  const int rg = blockIdx.x & 7;
  const int slot = (blockIdx.x >> 3) & 15;
  const int mtg = blockIdx.x >> 7;
  const int lane = tid & 63, wid = tid >> 6;
  const int mt = mtg * 8 + wid;

  const unsigned short* pa = (const unsigned short*)(ws + OFF_RINGF) +
                             ((size_t)slot * 8 + rg) * PANEL_US;
  const unsigned short* BFC = (const unsigned short*)(ws + OFF_FCB3);
  float* y = wsm + OFF_Y + (size_t)slot * (2048 * 192) + (size_t)(rg * 256) * 192;

  const int col = lane & 15, rb2 = (lane >> 4) * 4;

#pragma unroll 1
  for (int ng = 0; ng < 3; ng++) {
    f32x4 C[4];
#pragma unroll
    for (int j = 0; j < 4; j++) C[j] = (f32x4)0.0f;
#pragma unroll 1
    for (int kt = 0; kt < 8; kt++) {
      size_t fb = ((size_t)mt * 8 + kt) * 512 + lane * 8;
      s16x8 a0 = *(const s16x8*)(pa + fb);
      s16x8 a1 = *(const s16x8*)(pa + fb + SPOFF);
      s16x8 a2 = *(const s16x8*)(pa + fb + 2 * SPOFF);
#pragma unroll
      for (int n4 = 0; n4 < 4; n4++) {
        int nt = ng * 4 + n4;
        const unsigned short* bp = BFC + (size_t)(nt * 8 + kt) * (3 * 512) + lane * 8;
        s16x8 b0 = *(const s16x8*)(bp);
        s16x8 b1 = *(const s16x8*)(bp + 512);
        s16x8 b2 = *(const s16x8*)(bp + 1024);
        C[n4] = __builtin_amdgcn_mfma_f32_16x16x32_bf16(a0, b0, C[n4], 0, 0, 0);
        C[n4] = __builtin_amdgcn_mfma_f32_16x16x32_bf16(a0, b1, C[n4], 0, 0, 0);
        C[n4] = __builtin_amdgcn_mfma_f32_16x16x32_bf16(a1, b0, C[n4], 0, 0, 0);
        C[n4] = __builtin_amdgcn_mfma_f32_16x16x32_bf16(a1, b1, C[n4], 0, 0, 0);
        C[n4] = __builtin_amdgcn_mfma_f32_16x16x32_bf16(a0, b2, C[n4], 0, 0, 0);
        C[n4] = __builtin_amdgcn_mfma_f32_16x16x32_bf16(a2, b0, C[n4], 0, 0, 0);
      }
    }
#pragma unroll
    for (int n4 = 0; n4 < 4; n4++) {
      int c = (ng * 4 + n4) * 16 + col;
#pragma unroll
      for (int j = 0; j < 4; j++) {
        int mrow = mt * 16 + rb2 + j;
        y[(size_t)mrow * 192 + c] = C[n4][j];
      }
    }
  }
}

// Sampling: wave = one (slot,m) row; reads y, adds exact fp32 bias, runs MDN head.
__launch_bounds__(512, 2)
__global__ void vfpg_samp(const float* __restrict__ ws, const float* __restrict__ fcb,
                          float* __restrict__ out, int tbase,
                          uint32_t k1a, uint32_t k1b, uint32_t k2a, uint32_t k2b) {
  const int tid = threadIdx.x;
  const int lane = tid & 63, wid = tid >> 6;
  const int ridx = blockIdx.x * 8 + wid;       // 0..32767 = slot*2048 + m
  const int slot = ridx >> 11;
  const int m = ridx & 2047;

  const float* yrow = ws + OFF_Y + (size_t)ridx * 192;
  float yg = yrow[lane] + fcb[lane];
  float ys = yrow[64 + lane] + fcb[64 + lane];
  float ym = yrow[128 + lane] + fcb[128 + lane];

  uint32_t rid = (uint32_t)m * Tdim + (uint32_t)(tbase + slot);
  mdn_head(yg, ys, ym, lane, rid, k1a, k1b, k2a, k2b, out);
}

extern "C" void kernel_launch(void* const* d_in, const int* in_sizes, int n_in,
                              void* d_out, int out_size, void* d_ws, size_t ws_size,
                              hipStream_t stream) {
  const float* z    = (const float*)d_in[0];
  const float* Wih0 = (const float*)d_in[1];
  const float* Whh0 = (const float*)d_in[2];
  const float* bih0 = (const float*)d_in[3];
  const float* bhh0 = (const float*)d_in[4];
  const float* Wih1 = (const float*)d_in[5];
  const float* Whh1 = (const float*)d_in[6];
  const float* bih1 = (const float*)d_in[7];
  const float* bhh1 = (const float*)d_in[8];
  const float* fcW  = (const float*)d_in[9];
  const float* fcb  = (const float*)d_in[10];
  float* ws = (float*)d_ws;
  float* out = (float*)d_out;

  if (ws_size < (size_t)WS_TOT * sizeof(float)) return;

  vfpg_prep<<<dim3(512), dim3(256), 0, stream>>>(
      Wih0, Whh0, Wih1, Whh1, fcW, bih0, bhh0, bih1, bhh1, ws);

  uint32_t k1a, k1b, k2a, k2b;
  tf2x32(0u, 42u, 0u, 0u, &k1a, &k1b);
  tf2x32(0u, 42u, 0u, 1u, &k2a, &k2b);

  vfpg_step<0><<<dim3(256), dim3(512), 0, stream>>>(z, ws, ws, 0);
  for (int t = 1; t <= 63; t++) {
    vfpg_step<1><<<dim3(256), dim3(512), 0, stream>>>(z, ws, ws, t);
    if (t == 16 || t == 32 || t == 48) {
      vfpg_fc<<<dim3(256), dim3(512), 0, stream>>>(ws, ws);
      vfpg_samp<<<dim3(4096), dim3(512), 0, stream>>>(ws, fcb, out, t - 16,
                                                      k1a, k1b, k2a, k2b);
    }
  }
  vfpg_step<2><<<dim3(256), dim3(512), 0, stream>>>(z, ws, ws, 64);
  vfpg_fc<<<dim3(256), dim3(512), 0, stream>>>(ws, ws);
  vfpg_samp<<<dim3(4096), dim3(512), 0, stream>>>(ws, fcb, out, 48, k1a, k1b, k2a, k2b);
}